// Round 8
// baseline (659.482 us; speedup 1.0000x reference)
//
#include <hip/hip_runtime.h>

#define T_SEQ 1024
#define C_DIM 1024
#define H_DIM 4096
#define M_ROWS 16384   // P*B*T = 2*8*1024
#define CHUNKS 16
#define CLEN 64        // T_SEQ / CHUNKS

typedef _Float16 f16x8 __attribute__((ext_vector_type(8)));
typedef _Float16 f16x4 __attribute__((ext_vector_type(4)));
typedef float    f32x4 __attribute__((ext_vector_type(4)));

#define AS1 __attribute__((address_space(1)))
#define AS3 __attribute__((address_space(3)))

__device__ __forceinline__ void gload_lds16(const void* g, void* l) {
  __builtin_amdgcn_global_load_lds((const AS1 void*)g, (AS3 void*)l, 16, 0, 0);
}

__device__ __forceinline__ float sigmoidf_(float x) {
  return 1.0f / (1.0f + __expf(-x));
}

// ---------------- fused weight f32 -> f16 (all 7 weights, one launch) --------
struct CvtArgs {
  const float* src[7];
  _Float16*    dst[7];
  int n4[7];       // elements/4 per source
  int start[8];    // block-range prefix
};

__global__ __launch_bounds__(256) void cvt_all_kernel(CvtArgs a) {
  const int bid = blockIdx.x;
  int s = 0;
#pragma unroll
  for (int j = 0; j < 7; ++j) s += (bid >= a.start[j + 1]) ? 1 : 0;
  const int i = (bid - a.start[s]) * 256 + threadIdx.x;
  if (i >= a.n4[s]) return;
  f32x4 v = reinterpret_cast<const f32x4*>(a.src[s])[i];
  f16x4 o;
  o[0] = (_Float16)v[0]; o[1] = (_Float16)v[1];
  o[2] = (_Float16)v[2]; o[3] = (_Float16)v[3];
  reinterpret_cast<f16x4*>(a.dst[s])[i] = o;
}

// ---------------- layernorm: f32 in -> f16 out (one wave per row) ----------------
__global__ __launch_bounds__(256) void ln_kernel(const float* __restrict__ x,
    const float* __restrict__ g, const float* __restrict__ b,
    _Float16* __restrict__ h) {
  const int row  = blockIdx.x * 4 + (threadIdx.x >> 6);
  const int lane = threadIdx.x & 63;
  const f32x4* xr = reinterpret_cast<const f32x4*>(x + (size_t)row * C_DIM);
  f32x4 v[4];
  float s = 0.f, sq = 0.f;
#pragma unroll
  for (int i = 0; i < 4; ++i) {
    v[i] = xr[i * 64 + lane];
#pragma unroll
    for (int j = 0; j < 4; ++j) { s += v[i][j]; sq += v[i][j] * v[i][j]; }
  }
#pragma unroll
  for (int off = 32; off > 0; off >>= 1) {
    s  += __shfl_xor(s, off, 64);
    sq += __shfl_xor(sq, off, 64);
  }
  const float mu   = s * (1.0f / C_DIM);
  const float var  = sq * (1.0f / C_DIM) - mu * mu;
  const float rstd = rsqrtf(var + 1e-5f);
  const f32x4* g4 = reinterpret_cast<const f32x4*>(g);
  const f32x4* b4 = reinterpret_cast<const f32x4*>(b);
  f16x4* h4 = reinterpret_cast<f16x4*>(h + (size_t)row * C_DIM);
#pragma unroll
  for (int i = 0; i < 4; ++i) {
    f32x4 gg = g4[i * 64 + lane];
    f32x4 bb = b4[i * 64 + lane];
    f16x4 o;
#pragma unroll
    for (int j = 0; j < 4; ++j)
      o[j] = (_Float16)((v[i][j] - mu) * rstd * gg[j] + bb[j]);
    h4[i * 64 + lane] = o;
  }
}

// ---------------- time-shift mix, 3 outputs ----------------
__global__ __launch_bounds__(256) void mix3_kernel(const _Float16* __restrict__ h,
    const float* __restrict__ mk, const float* __restrict__ mv, const float* __restrict__ mr,
    _Float16* __restrict__ xk, _Float16* __restrict__ xv, _Float16* __restrict__ xr) {
  const int i  = blockIdx.x * 256 + threadIdx.x;   // [0, M_ROWS*128)
  const int m  = i >> 7;
  const int c0 = (i & 127) << 3;
  const int p  = m >> 13;
  const int t  = m & (T_SEQ - 1);
  const f16x8* h8 = reinterpret_cast<const f16x8*>(h);
  f16x8 hc = h8[i];
  f16x8 hp;
#pragma unroll
  for (int j = 0; j < 8; ++j) hp[j] = (_Float16)0.f;
  if (t) hp = h8[i - 128];
  f16x8 ok, ov, orr;
#pragma unroll
  for (int j = 0; j < 8; ++j) {
    const float hcf = (float)hc[j], hpf = (float)hp[j];
    const float a = mk[p * C_DIM + c0 + j];
    const float c = mv[p * C_DIM + c0 + j];
    const float d = mr[p * C_DIM + c0 + j];
    ok[j]  = (_Float16)(hcf * a + hpf * (1.f - a));
    ov[j]  = (_Float16)(hcf * c + hpf * (1.f - c));
    orr[j] = (_Float16)(hcf * d + hpf * (1.f - d));
  }
  reinterpret_cast<f16x8*>(xk)[i] = ok;
  reinterpret_cast<f16x8*>(xv)[i] = ov;
  reinterpret_cast<f16x8*>(xr)[i] = orr;
}

// ---------------- time-shift mix, 2 outputs ----------------
__global__ __launch_bounds__(256) void mix2_kernel(const _Float16* __restrict__ h,
    const float* __restrict__ mk, const float* __restrict__ mr,
    _Float16* __restrict__ xk, _Float16* __restrict__ xr) {
  const int i  = blockIdx.x * 256 + threadIdx.x;
  const int m  = i >> 7;
  const int c0 = (i & 127) << 3;
  const int p  = m >> 13;
  const int t  = m & (T_SEQ - 1);
  const f16x8* h8 = reinterpret_cast<const f16x8*>(h);
  f16x8 hc = h8[i];
  f16x8 hp;
#pragma unroll
  for (int j = 0; j < 8; ++j) hp[j] = (_Float16)0.f;
  if (t) hp = h8[i - 128];
  f16x8 ok, orr;
#pragma unroll
  for (int j = 0; j < 8; ++j) {
    const float hcf = (float)hc[j], hpf = (float)hp[j];
    const float a = mk[p * C_DIM + c0 + j];
    const float d = mr[p * C_DIM + c0 + j];
    ok[j]  = (_Float16)(hcf * a + hpf * (1.f - a));
    orr[j] = (_Float16)(hcf * d + hpf * (1.f - d));
  }
  reinterpret_cast<f16x8*>(xk)[i] = ok;
  reinterpret_cast<f16x8*>(xr)[i] = orr;
}

// ---------------- WKV parallel chunked scan, fused with a = sigmoid(r)*y -------
__global__ __launch_bounds__(1024, 1) void wkv_kernel(const _Float16* __restrict__ k,
    const _Float16* __restrict__ v, const _Float16* __restrict__ r,
    const float* __restrict__ td, const float* __restrict__ tf,
    _Float16* __restrict__ a_out) {
  __shared__ float sA[CHUNKS][64];
  __shared__ float sB[CHUNKS][64];
  __shared__ float sP[CHUNKS][64];
  const int tid   = threadIdx.x;
  const int chunk = tid >> 6;
  const int ch    = tid & 63;
  const int n     = blockIdx.x >> 4;     // 16 sequences
  const int cg    = blockIdx.x & 15;     // 16 channel groups of 64
  const int c     = cg * 64 + ch;
  const float w = -__expf(td[c]);
  const float u = tf[c];
  const size_t cbase = (size_t)n * T_SEQ * C_DIM + (size_t)chunk * CLEN * C_DIM + c;

  // ---- phase 1: local chunk scan from empty state (state only) ----
  float aa = 0.f, bb = 0.f, pp = -1e38f;
  for (int s = 0; s < CLEN; ++s) {
    const size_t idx = cbase + (size_t)s * C_DIM;
    const float kk = (float)k[idx];
    const float vv = (float)v[idx];
    const float ww2 = w + pp;
    const float p2  = fmaxf(ww2, kk);
    const float e1b = __expf(ww2 - p2);
    const float e2b = __expf(kk - p2);
    aa = e1b * aa + e2b * vv;
    bb = e1b * bb + e2b;
    pp = p2;
  }
  sA[chunk][ch] = aa; sB[chunk][ch] = bb; sP[chunk][ch] = pp;
  __syncthreads();

  // ---- phase 2: exclusive prefix across chunks ----
  if (chunk == 0) {
    float pa = 0.f, pb = 0.f, ppr = -1e38f;
    const float wL = w * (float)CLEN;
    for (int j = 0; j < CHUNKS; ++j) {
      const float la = sA[j][ch], lb = sB[j][ch], lp = sP[j][ch];
      sA[j][ch] = pa; sB[j][ch] = pb; sP[j][ch] = ppr;
      const float dp = wL + ppr;
      const float np = fmaxf(dp, lp);
      const float e1 = __expf(dp - np);
      const float e2 = __expf(lp - np);
      pa  = e1 * pa + e2 * la;
      pb  = e1 * pb + e2 * lb;
      ppr = np;
    }
  }
  __syncthreads();

  // ---- phase 3: re-scan chunk from prefix state, emit sigmoid(r)*y ----
  aa = sA[chunk][ch]; bb = sB[chunk][ch]; pp = sP[chunk][ch];
  for (int s = 0; s < CLEN; ++s) {
    const size_t idx = cbase + (size_t)s * C_DIM;
    const float kk = (float)k[idx];
    const float vv = (float)v[idx];
    const float ww = u + kk;
    const float p  = fmaxf(pp, ww);
    const float e1 = __expf(pp - p);
    const float e2 = __expf(ww - p);
    const float yv = __fdividef(e1 * aa + e2 * vv, e1 * bb + e2);
    const float sr = sigmoidf_((float)r[idx]);
    a_out[idx] = (_Float16)(sr * yv);
    const float ww2 = w + pp;
    const float p2  = fmaxf(ww2, kk);
    const float e1b = __expf(ww2 - p2);
    const float e2b = __expf(kk - p2);
    aa = e1b * aa + e2b * vv;
    bb = e1b * bb + e2b;
    pp = p2;
  }
}

// ======== 256x256 GEMM, 2-barrier tile + intra-wave counted-lgkm pipeline ========
// C[M,N] = A[M,K] * B[N,K]^T.  512 threads = 8 waves (2M x 4N), per-wave
// 128x64 output, BK=64, double-buffered LDS (128 KiB).
// Per K-tile t (buf bi): stage tile t+1 (8 gload_lds) -> vmcnt(8) (tile t
// landed, t+1 in flight) -> barrier -> queue reads in groups with counted
// lgkmcnt between 16-MFMA clusters, so each cluster's execution hides the
// next group's LDS latency, and the LDS/matrix pipes stay co-busy. Only 2
// barriers per tile: the intra-tile barriers of R7 were correctness-
// unnecessary (no cross-wave hazard within a tile) and lockstepped waves
// into read-burst/MFMA-burst alternation (the 38% ceiling).
// Read/wait ledger per wave (24 ds_read_b128 total):
//   issue a0k0(4) bk0(4) a0k1(4) bk1(4)   [16 out]
//   lgkm(8)  -> a0k0,bk0 ready  | MMC(a0,k0, accRows0-3)
//   issue a1k0(4)                [<=12 out]
//   lgkm(4+4=8 -> forces a0k1)  ... then lgkm(4) forces bk1, keeps a1k0
//   MMC(a0,k1)
//   issue a1k1(4); lgkm(4) -> a1k0 | MMC(a1,k0, accRows4-7)
//   lgkm(0) -> a1k1              | MMC(a1,k1)
// Waves desync across the tile body -> natural read/MFMA overlap across
// waves too (and setprio has roles to arbitrate, T5).
// Batching: blockIdx.z selects A/B/C by stride (k,v,r projections fused
// into one launch).
// EPI 0: f16; 1: f16(relu^2); 2: f32 acc+X; 3: f32 X + sigmoid(acc)*KV
#define GBAR() do { __builtin_amdgcn_sched_barrier(0); \
                    __builtin_amdgcn_s_barrier(); \
                    __builtin_amdgcn_sched_barrier(0); } while (0)
#define WVN(n) do { asm volatile("s_waitcnt vmcnt(" #n ")" ::: "memory"); \
                    __builtin_amdgcn_sched_barrier(0); } while (0)
#define WLN(n) do { asm volatile("s_waitcnt lgkmcnt(" #n ")" ::: "memory"); \
                    __builtin_amdgcn_sched_barrier(0); } while (0)
#define SCHED() __builtin_amdgcn_sched_barrier(0)
#define STAGE(op, SRC, row0, k0, bb) do { \
    _Pragma("unroll") \
    for (int c_ = 0; c_ < 2; ++c_) { \
      gload_lds16((SRC) + (size_t)((row0) + c_ * 64) * K + (k0), \
                  &lds[bb][op][((size_t)((row0) + c_ * 64) << 6) + dbase]); \
    } } while (0)
#define RD_A4(dst, mh, kk_) do { \
    _Pragma("unroll") for (int i_ = 0; i_ < 4; ++i_) \
      dst[i_][kk_] = *reinterpret_cast<const f16x8*>( \
        &lds[bi][0][((wr * 128 + (mh) * 64 + i_ * 16 + frow) << 6) + \
                    ((((kk_) << 5) + fk) ^ fxorh)]); \
  } while (0)
#define RD_B4(kk_) do { \
    _Pragma("unroll") for (int j_ = 0; j_ < 4; ++j_) \
      bf[j_][kk_] = *reinterpret_cast<const f16x8*>( \
        &lds[bi][1][((wcn * 64 + j_ * 16 + frow) << 6) + \
                    ((((kk_) << 5) + fk) ^ fxorh)]); \
  } while (0)
#define MMC(asrc, kk_, half) do { \
    __builtin_amdgcn_s_setprio(1); \
    _Pragma("unroll") for (int i_ = 0; i_ < 4; ++i_) \
    _Pragma("unroll") for (int j_ = 0; j_ < 4; ++j_) \
      acc[(half) * 4 + i_][j_] = __builtin_amdgcn_mfma_f32_16x16x32_f16( \
        asrc[i_][kk_], bf[j_][kk_], acc[(half) * 4 + i_][j_], 0, 0, 0); \
    __builtin_amdgcn_s_setprio(0); \
  } while (0)

template<int EPI>
__global__ __launch_bounds__(512, 2) void gemm_nt_256(
    const _Float16* __restrict__ A, const _Float16* __restrict__ B,
    void* __restrict__ Cv, const float* __restrict__ X,
    const _Float16* __restrict__ KV, int M, int N, int K,
    size_t strideA, size_t strideB, size_t strideCbytes) {
  __shared__ _Float16 lds[2][2][256 * 64];
  const int tid  = threadIdx.x;
  const int wave = tid >> 6;
  const int lane = tid & 63;
  const int wr   = wave >> 2;     // 0..1
  const int wcn  = wave & 3;      // 0..3

  A  = A + (size_t)blockIdx.z * strideA;
  B  = B + (size_t)blockIdx.z * strideB;
  Cv = (void*)((char*)Cv + (size_t)blockIdx.z * strideCbytes);

  // XCD-bijective swizzle: XCD owns contiguous M chunk, n-fastest within.
  const unsigned nwx  = gridDim.x;        // N/256
  const unsigned pery = gridDim.y >> 3;   // m-tiles per XCD
  const unsigned id   = blockIdx.y * nwx + blockIdx.x;
  const unsigned xcd  = id & 7;
  const unsigned loc  = id >> 3;
  const size_t m0 = (size_t)(xcd * pery + loc / nwx) * 256;
  const size_t n0 = (size_t)(loc % nwx) * 256;

  // staging geometry: half-tile = 128 rows x 64 halfs; wave w covers rows
  // {row0 + c*64 + w*8 .. +7}; LDS dest is wave-uniform base + lane*16B.
  const int srow  = tid >> 3;                       // 0..63
  const int scolh = ((tid & 7) ^ (srow & 7)) << 3;  // source-swizzled col (halfs)
  const size_t dbase = (size_t)(srow & ~7) << 6;    // wave-uniform
  const _Float16* sA = A + (m0 + srow) * (size_t)K + scolh;
  const _Float16* sB = B + (n0 + srow) * (size_t)K + scolh;

  // fragment geometry
  const int frow  = lane & 15;
  const int fk    = (lane >> 4) << 3;
  const int fxorh = (frow & 7) << 3;

  f32x4 acc[8][4];
#pragma unroll
  for (int i = 0; i < 8; ++i)
#pragma unroll
    for (int j = 0; j < 4; ++j) acc[i][j] = (f32x4){0.f, 0.f, 0.f, 0.f};

  // prologue: stage tile 0 -> buf 0 (8 loads/wave outstanding)
  STAGE(0, sA, 0, 0, 0); STAGE(0, sA, 128, 0, 0);
  STAGE(1, sB, 0, 0, 0); STAGE(1, sB, 128, 0, 0);

  const int NT = K >> 6;
  for (int t = 0; t < NT; ++t) {
    const int bi = t & 1;
    const int nb = bi ^ 1;
    const int k1 = (t + 1) << 6;
    if (t + 1 < NT) {
      // stage tile t+1 into the other buffer; its 8 loads stay in flight
      STAGE(0, sA, 0, k1, nb); STAGE(0, sA, 128, k1, nb);
      STAGE(1, sB, 0, k1, nb); STAGE(1, sB, 128, k1, nb);
      WVN(8);          // tile t's 8 loads landed; t+1's 8 in flight
    } else {
      WVN(0);          // last tile: drain
    }
    GBAR();
    f16x8 a0[4][2], a1[4][2], bf[4][2];
    RD_A4(a0, 0, 0); SCHED();
    RD_B4(0);        SCHED();
    RD_A4(a0, 0, 1); SCHED();
    RD_B4(1);        SCHED();          // 16 reads queued
    WLN(8);                            // a0k0 + bk0 landed
    MMC(a0, 0, 0);                     // 16 MFMA; hides a0k1+bk1
    RD_A4(a1, 1, 0); SCHED();          // +4 reads in flight
    WLN(4);                            // a0k1 + bk1 landed, a1k0 flying
    MMC(a0, 1, 0);                     // hides a1k0
    RD_A4(a1, 1, 1); SCHED();          // +4 reads
    WLN(4);                            // a1k0 landed, a1k1 flying
    MMC(a1, 0, 1);                     // hides a1k1
    WLN(0);
    MMC(a1, 1, 1);
    GBAR();
  }

  // epilogue: C/D layout (16x16): col = lane&15, row = (lane>>4)*4 + reg
  const int ecol  = lane & 15;
  const int erow4 = (lane >> 4) * 4;
#pragma unroll
  for (int mf = 0; mf < 8; ++mf)
#pragma unroll
    for (int nf = 0; nf < 4; ++nf) {
      const size_t rbase = m0 + (size_t)(wr * 128 + mf * 16 + erow4);
      const size_t cc    = n0 + (size_t)(wcn * 64 + nf * 16 + ecol);
#pragma unroll
      for (int r = 0; r < 4; ++r) {
        const float val = acc[mf][nf][r];
        const size_t off = (rbase + r) * (size_t)N + cc;
        if constexpr (EPI == 0) {
          ((_Float16*)Cv)[off] = (_Float16)val;
        } else if constexpr (EPI == 1) {
          const float tq = fmaxf(val, 0.f);
          ((_Float16*)Cv)[off] = (_Float16)(tq * tq);
        } else if constexpr (EPI == 2) {
          ((float*)Cv)[off] = val + X[off];
        } else {
          ((float*)Cv)[off] = X[off] + sigmoidf_(val) * (float)KV[off];
        }
      }
    }
}

extern "C" void kernel_launch(void* const* d_in, const int* in_sizes, int n_in,
                              void* d_out, int out_size, void* d_ws, size_t ws_size,
                              hipStream_t stream) {
  const float* x      = (const float*)d_in[0];
  const float* ln1_g  = (const float*)d_in[1];
  const float* ln1_b  = (const float*)d_in[2];
  const float* ln2_g  = (const float*)d_in[3];
  const float* ln2_b  = (const float*)d_in[4];
  const float* tdec   = (const float*)d_in[5];
  const float* tfirst = (const float*)d_in[6];
  const float* amk    = (const float*)d_in[7];
  const float* amv    = (const float*)d_in[8];
  const float* amr    = (const float*)d_in[9];
  const float* Wk     = (const float*)d_in[10];
  const float* Wv     = (const float*)d_in[11];
  const float* Wr     = (const float*)d_in[12];
  const float* Wo     = (const float*)d_in[13];
  const float* cmk    = (const float*)d_in[14];
  const float* cmr    = (const float*)d_in[15];
  const float* Wck    = (const float*)d_in[16];
  const float* Wcr    = (const float*)d_in[17];
  const float* Wcv    = (const float*)d_in[18];

  char* ws = (char*)d_ws;
  const size_t SZ = (size_t)M_ROWS * C_DIM * sizeof(_Float16);  // 32 MiB
  _Float16* B0 = (_Float16*)(ws + 0 * SZ);
  _Float16* B1 = (_Float16*)(ws + 1 * SZ);
  _Float16* B2 = (_Float16*)(ws + 2 * SZ);
  _Float16* B3 = (_Float16*)(ws + 3 * SZ);   // kk spans B3..B6 (128 MiB)
  _Float16* B4 = (_Float16*)(ws + 4 * SZ);
  _Float16* B5 = (_Float16*)(ws + 5 * SZ);
  _Float16* B6 = (_Float16*)(ws + 6 * SZ);
  _Float16* wWk  = (_Float16*)(ws + 7 * SZ);
  _Float16* wWv  = wWk  + (size_t)C_DIM * C_DIM;
  _Float16* wWr  = wWv  + (size_t)C_DIM * C_DIM;
  _Float16* wWo  = wWr  + (size_t)C_DIM * C_DIM;
  _Float16* wWcr = wWo  + (size_t)C_DIM * C_DIM;
  _Float16* wWck = wWcr + (size_t)C_DIM * C_DIM;
  _Float16* wWcv = wWck + (size_t)H_DIM * C_DIM;

  // fused weight cast: one launch for all 7 weights
  {
    CvtArgs a;
    const float* srcs[7] = {Wk, Wv, Wr, Wo, Wcr, Wck, Wcv};
    _Float16*    dsts[7] = {wWk, wWv, wWr, wWo, wWcr, wWck, wWcv};
    const size_t ns[7]   = {(size_t)C_DIM * C_DIM, (size_t)C_DIM * C_DIM,
                            (size_t)C_DIM * C_DIM, (size_t)C_DIM * C_DIM,
                            (size_t)C_DIM * C_DIM, (size_t)H_DIM * C_DIM,
                            (size_t)C_DIM * H_DIM};
    int st = 0;
    for (int j = 0; j < 7; ++j) {
      a.src[j] = srcs[j]; a.dst[j] = dsts[j];
      a.n4[j] = (int)(ns[j] / 4);
      a.start[j] = st;
      st += (a.n4[j] + 255) / 256;
    }
    a.start[7] = st;
    cvt_all_kernel<<<dim3(st), dim3(256), 0, stream>>>(a);
  }

  const dim3 blk(256);
  const dim3 gblk(512);
  const dim3 gN1(C_DIM / 256, M_ROWS / 256);      // (4, 64)
  const dim3 gKVR(C_DIM / 256, M_ROWS / 256, 3);  // batched k,v,r
  const dim3 gN4(H_DIM / 256, M_ROWS / 256);      // (16, 64)

  // --- TimeMix ---
  ln_kernel<<<dim3(M_ROWS / 4), blk, 0, stream>>>(x, ln1_g, ln1_b, B0);
  mix3_kernel<<<dim3(M_ROWS * 128 / 256), blk, 0, stream>>>(B0, amk, amv, amr, B1, B2, B3);
  // batched k,v,r projections: A = {B1,B2,B3}, B = {wWk,wWv,wWr}, C = {B4,B5,B6}
  gemm_nt_256<0><<<gKVR, gblk, 0, stream>>>(B1, wWk, B4, nullptr, nullptr,
      M_ROWS, C_DIM, C_DIM,
      (size_t)M_ROWS * C_DIM, (size_t)C_DIM * C_DIM,
      (size_t)M_ROWS * C_DIM * sizeof(_Float16));
  wkv_kernel<<<dim3(256), dim3(1024), 0, stream>>>(B4, B5, B6, tdec, tfirst, B1);
  gemm_nt_256<2><<<gN1, gblk, 0, stream>>>(B1, wWo, d_out, x, nullptr,
      M_ROWS, C_DIM, C_DIM, 0, 0, 0);

  // --- ChannelMix ---
  ln_kernel<<<dim3(M_ROWS / 4), blk, 0, stream>>>((const float*)d_out, ln2_g, ln2_b, B0);
  mix2_kernel<<<dim3(M_ROWS * 128 / 256), blk, 0, stream>>>(B0, cmk, cmr, B1, B2);
  gemm_nt_256<1><<<gN4, gblk, 0, stream>>>(B1, wWck, B3, nullptr, nullptr,
      M_ROWS, H_DIM, C_DIM, 0, 0, 0);
  gemm_nt_256<0><<<gN1, gblk, 0, stream>>>(B3, wWcv, B1, nullptr, nullptr,
      M_ROWS, C_DIM, H_DIM, 0, 0, 0);
  gemm_nt_256<3><<<gN1, gblk, 0, stream>>>(B2, wWcr, d_out, (const float*)d_out, B1,
      M_ROWS, C_DIM, C_DIM, 0, 0, 0);
}

// Round 9
// 654.590 us; speedup vs baseline: 1.0075x; 1.0075x over previous
//
#include <hip/hip_runtime.h>

#define T_SEQ 1024
#define C_DIM 1024
#define H_DIM 4096
#define M_ROWS 16384   // P*B*T = 2*8*1024
#define CHUNKS 16
#define CLEN 64        // T_SEQ / CHUNKS

typedef _Float16 f16x8 __attribute__((ext_vector_type(8)));
typedef _Float16 f16x4 __attribute__((ext_vector_type(4)));
typedef float    f32x4 __attribute__((ext_vector_type(4)));

#define AS1 __attribute__((address_space(1)))
#define AS3 __attribute__((address_space(3)))

__device__ __forceinline__ void gload_lds16(const void* g, void* l) {
  __builtin_amdgcn_global_load_lds((const AS1 void*)g, (AS3 void*)l, 16, 0, 0);
}

__device__ __forceinline__ float sigmoidf_(float x) {
  return 1.0f / (1.0f + __expf(-x));
}

// ---------------- fused weight f32 -> f16 (all 7 weights, one launch) --------
struct CvtArgs {
  const float* src[7];
  _Float16*    dst[7];
  int n4[7];       // elements/4 per source
  int start[8];    // block-range prefix
};

__global__ __launch_bounds__(256) void cvt_all_kernel(CvtArgs a) {
  const int bid = blockIdx.x;
  int s = 0;
#pragma unroll
  for (int j = 0; j < 7; ++j) s += (bid >= a.start[j + 1]) ? 1 : 0;
  const int i = (bid - a.start[s]) * 256 + threadIdx.x;
  if (i >= a.n4[s]) return;
  f32x4 v = reinterpret_cast<const f32x4*>(a.src[s])[i];
  f16x4 o;
  o[0] = (_Float16)v[0]; o[1] = (_Float16)v[1];
  o[2] = (_Float16)v[2]; o[3] = (_Float16)v[3];
  reinterpret_cast<f16x4*>(a.dst[s])[i] = o;
}

// ---------------- layernorm: f32 in -> f16 out (one wave per row) ----------------
__global__ __launch_bounds__(256) void ln_kernel(const float* __restrict__ x,
    const float* __restrict__ g, const float* __restrict__ b,
    _Float16* __restrict__ h) {
  const int row  = blockIdx.x * 4 + (threadIdx.x >> 6);
  const int lane = threadIdx.x & 63;
  const f32x4* xr = reinterpret_cast<const f32x4*>(x + (size_t)row * C_DIM);
  f32x4 v[4];
  float s = 0.f, sq = 0.f;
#pragma unroll
  for (int i = 0; i < 4; ++i) {
    v[i] = xr[i * 64 + lane];
#pragma unroll
    for (int j = 0; j < 4; ++j) { s += v[i][j]; sq += v[i][j] * v[i][j]; }
  }
#pragma unroll
  for (int off = 32; off > 0; off >>= 1) {
    s  += __shfl_xor(s, off, 64);
    sq += __shfl_xor(sq, off, 64);
  }
  const float mu   = s * (1.0f / C_DIM);
  const float var  = sq * (1.0f / C_DIM) - mu * mu;
  const float rstd = rsqrtf(var + 1e-5f);
  const f32x4* g4 = reinterpret_cast<const f32x4*>(g);
  const f32x4* b4 = reinterpret_cast<const f32x4*>(b);
  f16x4* h4 = reinterpret_cast<f16x4*>(h + (size_t)row * C_DIM);
#pragma unroll
  for (int i = 0; i < 4; ++i) {
    f32x4 gg = g4[i * 64 + lane];
    f32x4 bb = b4[i * 64 + lane];
    f16x4 o;
#pragma unroll
    for (int j = 0; j < 4; ++j)
      o[j] = (_Float16)((v[i][j] - mu) * rstd * gg[j] + bb[j]);
    h4[i * 64 + lane] = o;
  }
}

// ---------------- time-shift mix, 3 outputs ----------------
__global__ __launch_bounds__(256) void mix3_kernel(const _Float16* __restrict__ h,
    const float* __restrict__ mk, const float* __restrict__ mv, const float* __restrict__ mr,
    _Float16* __restrict__ xk, _Float16* __restrict__ xv, _Float16* __restrict__ xr) {
  const int i  = blockIdx.x * 256 + threadIdx.x;   // [0, M_ROWS*128)
  const int m  = i >> 7;
  const int c0 = (i & 127) << 3;
  const int p  = m >> 13;
  const int t  = m & (T_SEQ - 1);
  const f16x8* h8 = reinterpret_cast<const f16x8*>(h);
  f16x8 hc = h8[i];
  f16x8 hp;
#pragma unroll
  for (int j = 0; j < 8; ++j) hp[j] = (_Float16)0.f;
  if (t) hp = h8[i - 128];
  f16x8 ok, ov, orr;
#pragma unroll
  for (int j = 0; j < 8; ++j) {
    const float hcf = (float)hc[j], hpf = (float)hp[j];
    const float a = mk[p * C_DIM + c0 + j];
    const float c = mv[p * C_DIM + c0 + j];
    const float d = mr[p * C_DIM + c0 + j];
    ok[j]  = (_Float16)(hcf * a + hpf * (1.f - a));
    ov[j]  = (_Float16)(hcf * c + hpf * (1.f - c));
    orr[j] = (_Float16)(hcf * d + hpf * (1.f - d));
  }
  reinterpret_cast<f16x8*>(xk)[i] = ok;
  reinterpret_cast<f16x8*>(xv)[i] = ov;
  reinterpret_cast<f16x8*>(xr)[i] = orr;
}

// ---------------- time-shift mix, 2 outputs ----------------
__global__ __launch_bounds__(256) void mix2_kernel(const _Float16* __restrict__ h,
    const float* __restrict__ mk, const float* __restrict__ mr,
    _Float16* __restrict__ xk, _Float16* __restrict__ xr) {
  const int i  = blockIdx.x * 256 + threadIdx.x;
  const int m  = i >> 7;
  const int c0 = (i & 127) << 3;
  const int p  = m >> 13;
  const int t  = m & (T_SEQ - 1);
  const f16x8* h8 = reinterpret_cast<const f16x8*>(h);
  f16x8 hc = h8[i];
  f16x8 hp;
#pragma unroll
  for (int j = 0; j < 8; ++j) hp[j] = (_Float16)0.f;
  if (t) hp = h8[i - 128];
  f16x8 ok, orr;
#pragma unroll
  for (int j = 0; j < 8; ++j) {
    const float hcf = (float)hc[j], hpf = (float)hp[j];
    const float a = mk[p * C_DIM + c0 + j];
    const float d = mr[p * C_DIM + c0 + j];
    ok[j]  = (_Float16)(hcf * a + hpf * (1.f - a));
    orr[j] = (_Float16)(hcf * d + hpf * (1.f - d));
  }
  reinterpret_cast<f16x8*>(xk)[i] = ok;
  reinterpret_cast<f16x8*>(xr)[i] = orr;
}

// ---------------- WKV parallel chunked scan, fused with a = sigmoid(r)*y -------
__global__ __launch_bounds__(1024, 1) void wkv_kernel(const _Float16* __restrict__ k,
    const _Float16* __restrict__ v, const _Float16* __restrict__ r,
    const float* __restrict__ td, const float* __restrict__ tf,
    _Float16* __restrict__ a_out) {
  __shared__ float sA[CHUNKS][64];
  __shared__ float sB[CHUNKS][64];
  __shared__ float sP[CHUNKS][64];
  const int tid   = threadIdx.x;
  const int chunk = tid >> 6;
  const int ch    = tid & 63;
  const int n     = blockIdx.x >> 4;     // 16 sequences
  const int cg    = blockIdx.x & 15;     // 16 channel groups of 64
  const int c     = cg * 64 + ch;
  const float w = -__expf(td[c]);
  const float u = tf[c];
  const size_t cbase = (size_t)n * T_SEQ * C_DIM + (size_t)chunk * CLEN * C_DIM + c;

  // ---- phase 1: local chunk scan from empty state (state only) ----
  float aa = 0.f, bb = 0.f, pp = -1e38f;
  for (int s = 0; s < CLEN; ++s) {
    const size_t idx = cbase + (size_t)s * C_DIM;
    const float kk = (float)k[idx];
    const float vv = (float)v[idx];
    const float ww2 = w + pp;
    const float p2  = fmaxf(ww2, kk);
    const float e1b = __expf(ww2 - p2);
    const float e2b = __expf(kk - p2);
    aa = e1b * aa + e2b * vv;
    bb = e1b * bb + e2b;
    pp = p2;
  }
  sA[chunk][ch] = aa; sB[chunk][ch] = bb; sP[chunk][ch] = pp;
  __syncthreads();

  // ---- phase 2: exclusive prefix across chunks ----
  if (chunk == 0) {
    float pa = 0.f, pb = 0.f, ppr = -1e38f;
    const float wL = w * (float)CLEN;
    for (int j = 0; j < CHUNKS; ++j) {
      const float la = sA[j][ch], lb = sB[j][ch], lp = sP[j][ch];
      sA[j][ch] = pa; sB[j][ch] = pb; sP[j][ch] = ppr;
      const float dp = wL + ppr;
      const float np = fmaxf(dp, lp);
      const float e1 = __expf(dp - np);
      const float e2 = __expf(lp - np);
      pa  = e1 * pa + e2 * la;
      pb  = e1 * pb + e2 * lb;
      ppr = np;
    }
  }
  __syncthreads();

  // ---- phase 3: re-scan chunk from prefix state, emit sigmoid(r)*y ----
  aa = sA[chunk][ch]; bb = sB[chunk][ch]; pp = sP[chunk][ch];
  for (int s = 0; s < CLEN; ++s) {
    const size_t idx = cbase + (size_t)s * C_DIM;
    const float kk = (float)k[idx];
    const float vv = (float)v[idx];
    const float ww = u + kk;
    const float p  = fmaxf(pp, ww);
    const float e1 = __expf(pp - p);
    const float e2 = __expf(ww - p);
    const float yv = __fdividef(e1 * aa + e2 * vv, e1 * bb + e2);
    const float sr = sigmoidf_((float)r[idx]);
    a_out[idx] = (_Float16)(sr * yv);
    const float ww2 = w + pp;
    const float p2  = fmaxf(ww2, kk);
    const float e1b = __expf(ww2 - p2);
    const float e2b = __expf(kk - p2);
    aa = e1b * aa + e2b * vv;
    bb = e1b * bb + e2b;
    pp = p2;
  }
}

// ======== 256x256 GEMM, K-SPLIT stage units + 2-gate counted-vmcnt pipeline ========
// C[M,N] = A[M,K] * B[N,K]^T.  512 threads = 8 waves (2M x 4N), per-wave
// 128x64 output, BK=64, double-buffered LDS [2][2][2][256][32] halfs:
// [buf][op A/B][khalf][row][col] — stage units are K-SPLIT (U0=A-k0..31,
// U1=B-k0..31, U2=A-k32..63, U3=B-k32..63; 16 KiB each, 2 gload_lds/wave),
// so every wave needs the SAME units at the same segment -> wave-uniform
// gating at HALF-tile granularity (the m201 ledger, finally consistent).
// Per tile t (buf bi), 2 segments (kh=0,1); each:
//   stage 1 unit of t+1 -> vmcnt(6) [forces this segment's 2 units of t
//   retired, keeps 3 units in flight] -> barrier -> 12 ds_reads in groups
//   (8 then 4) -> lgkm(4) -> 16 MFMA -> lgkm(0) -> 16 MFMA; 2nd stage
//   mid-segment. 2 barriers/tile; in-flight never <6 loads except final
//   drain. Buffer overwrites barrier-separated (kh regions alternate).
// Swizzle: global-source slot XOR (rule 21) + same XOR on ds_read;
// 2-way max bank aliasing (free).
// EPI 0: f16; 1: f16(relu^2); 2: f32 acc+X; 3: f32 X + sigmoid(acc)*KV
#define GBAR() do { __builtin_amdgcn_sched_barrier(0); \
                    __builtin_amdgcn_s_barrier(); \
                    __builtin_amdgcn_sched_barrier(0); } while (0)
#define WVN(n) do { asm volatile("s_waitcnt vmcnt(" #n ")" ::: "memory"); \
                    __builtin_amdgcn_sched_barrier(0); } while (0)
#define WLN(n) do { asm volatile("s_waitcnt lgkmcnt(" #n ")" ::: "memory"); \
                    __builtin_amdgcn_sched_barrier(0); } while (0)
#define SCHED() __builtin_amdgcn_sched_barrier(0)
// stage unit (op, khalf) of the tile starting at column k0 into buffer bb:
// two sweeps g=0 (rows 0-127), g=1 (rows 128-255); LDS dest wave-uniform.
#define STAGEU(op, SRCP, kh, k0, bb) do { \
    gload_lds16((SRCP) + (kh) * 32 + (k0), &lds[bb][op][kh][wave * 16][0]); \
    gload_lds16((SRCP) + (size_t)128 * K + (kh) * 32 + (k0), \
                &lds[bb][op][kh][128 + wave * 16][0]); \
  } while (0)
#define RD_A4K(dst, mbase, kh) do { \
    _Pragma("unroll") for (int i_ = 0; i_ < 4; ++i_) \
      dst[i_] = *reinterpret_cast<const f16x8*>( \
        &lds[bi][0][kh][wr * 128 + ((mbase) + i_) * 16 + frow][rdoffH]); \
  } while (0)
#define RD_B4K(dst, kh) do { \
    _Pragma("unroll") for (int j_ = 0; j_ < 4; ++j_) \
      dst[j_] = *reinterpret_cast<const f16x8*>( \
        &lds[bi][1][kh][wcn * 64 + j_ * 16 + frow][rdoffH]); \
  } while (0)
#define MMC4(asrc, bsrc, rbase) do { \
    __builtin_amdgcn_s_setprio(1); \
    _Pragma("unroll") for (int i_ = 0; i_ < 4; ++i_) \
    _Pragma("unroll") for (int j_ = 0; j_ < 4; ++j_) \
      acc[(rbase) + i_][j_] = __builtin_amdgcn_mfma_f32_16x16x32_f16( \
        asrc[i_], bsrc[j_], acc[(rbase) + i_][j_], 0, 0, 0); \
    __builtin_amdgcn_s_setprio(0); \
  } while (0)
// one segment (khalf KH); stages U_A' then U_B' of tile t+1
#define SEGMENT(KH, WLAST) do { \
    if (st) { STAGEU(0, sA, KH, k1, nb); WVN(6); } else { WVN(WLAST); } \
    GBAR(); \
    f16x8 a0[4], a1[4], b0[4]; \
    RD_A4K(a0, 0, KH); RD_B4K(b0, KH); SCHED(); \
    RD_A4K(a1, 4, KH); SCHED(); \
    if (st) STAGEU(1, sB, KH, k1, nb); \
    WLN(4); \
    MMC4(a0, b0, 0); \
    WLN(0); \
    MMC4(a1, b0, 4); \
  } while (0)

template<int EPI>
__global__ __launch_bounds__(512, 2) void gemm_nt_256(
    const _Float16* __restrict__ A, const _Float16* __restrict__ B,
    void* __restrict__ Cv, const float* __restrict__ X,
    const _Float16* __restrict__ KV, int M, int N, int K,
    size_t strideA, size_t strideB, size_t strideCbytes) {
  __shared__ _Float16 lds[2][2][2][256][32];  // [buf][op][kh][row][colhalf]
  const int tid  = threadIdx.x;
  const int wave = tid >> 6;
  const int lane = tid & 63;
  const int wr   = wave >> 2;     // 0..1
  const int wcn  = wave & 3;      // 0..3

  A  = A + (size_t)blockIdx.z * strideA;
  B  = B + (size_t)blockIdx.z * strideB;
  Cv = (void*)((char*)Cv + (size_t)blockIdx.z * strideCbytes);

  // XCD-bijective swizzle: XCD owns contiguous M chunk, n-fastest within.
  const unsigned nwx  = gridDim.x;        // N/256
  const unsigned pery = gridDim.y >> 3;   // m-tiles per XCD
  const unsigned id   = blockIdx.y * nwx + blockIdx.x;
  const unsigned xcd  = id & 7;
  const unsigned loc  = id >> 3;
  const size_t m0 = (size_t)(xcd * pery + loc / nwx) * 256;
  const size_t n0 = (size_t)(loc % nwx) * 256;

  // staging geometry (k-split unit = 256 rows x 32 halfs; sweep g covers
  // 128 rows; per sweep: thread -> row = g*128 + wave*16 + (lane>>2),
  // source col-slot = (lane&3) XOR-swizzled; LDS dest linear).
  const int srowS   = wave * 16 + (lane >> 2);
  const int srcslot = (lane & 3) ^ (((lane >> 2) ^ (lane >> 4)) & 3);
  const _Float16* sA = A + (m0 + srowS) * (size_t)K + srcslot * 8;
  const _Float16* sB = B + (n0 + srowS) * (size_t)K + srcslot * 8;

  // fragment geometry: frag row = base + frow; read slot = fslot ^ x2(row),
  // x2 = (frow ^ (frow>>2)) & 3 (row-base bits vanish mod 16).
  const int frow   = lane & 15;
  const int rdoffH = (((lane >> 4) ^ ((frow ^ (frow >> 2)) & 3)) << 3);

  f32x4 acc[8][4];
#pragma unroll
  for (int i = 0; i < 8; ++i)
#pragma unroll
    for (int j = 0; j < 4; ++j) acc[i][j] = (f32x4){0.f, 0.f, 0.f, 0.f};

  // prologue: stage tile 0's four units (FIFO order U0,U1,U2,U3) into buf 0
  STAGEU(0, sA, 0, 0, 0);
  STAGEU(1, sB, 0, 0, 0);
  STAGEU(0, sA, 1, 0, 0);
  STAGEU(1, sB, 1, 0, 0);

  const int NT = K >> 6;
  for (int t = 0; t < NT; ++t) {
    const int bi = t & 1;
    const int nb = bi ^ 1;
    const int k1 = (t + 1) << 6;
    const bool st = (t + 1) < NT;
    SEGMENT(0, 4);   // kh=0: gate forces U0,U1 of t; last tile: vmcnt(4)
    SEGMENT(1, 0);   // kh=1: gate forces U2,U3 of t; last tile: vmcnt(0)
  }

  // epilogue: C/D layout (16x16): col = lane&15, row = (lane>>4)*4 + reg
  const int ecol  = lane & 15;
  const int erow4 = (lane >> 4) * 4;
#pragma unroll
  for (int mf = 0; mf < 8; ++mf)
#pragma unroll
    for (int nf = 0; nf < 4; ++nf) {
      const size_t rbase = m0 + (size_t)(wr * 128 + mf * 16 + erow4);
      const size_t cc    = n0 + (size_t)(wcn * 64 + nf * 16 + ecol);
#pragma unroll
      for (int r = 0; r < 4; ++r) {
        const float val = acc[mf][nf][r];
        const size_t off = (rbase + r) * (size_t)N + cc;
        if constexpr (EPI == 0) {
          ((_Float16*)Cv)[off] = (_Float16)val;
        } else if constexpr (EPI == 1) {
          const float tq = fmaxf(val, 0.f);
          ((_Float16*)Cv)[off] = (_Float16)(tq * tq);
        } else if constexpr (EPI == 2) {
          ((float*)Cv)[off] = val + X[off];
        } else {
          ((float*)Cv)[off] = X[off] + sigmoidf_(val) * (float)KV[off];
        }
      }
    }
}

extern "C" void kernel_launch(void* const* d_in, const int* in_sizes, int n_in,
                              void* d_out, int out_size, void* d_ws, size_t ws_size,
                              hipStream_t stream) {
  const float* x      = (const float*)d_in[0];
  const float* ln1_g  = (const float*)d_in[1];
  const float* ln1_b  = (const float*)d_in[2];
  const float* ln2_g  = (const float*)d_in[3];
  const float* ln2_b  = (const float*)d_in[4];
  const float* tdec   = (const float*)d_in[5];
  const float* tfirst = (const float*)d_in[6];
  const float* amk    = (const float*)d_in[7];
  const float* amv    = (const float*)d_in[8];
  const float* amr    = (const float*)d_in[9];
  const float* Wk     = (const float*)d_in[10];
  const float* Wv     = (const float*)d_in[11];
  const float* Wr     = (const float*)d_in[12];
  const float* Wo     = (const float*)d_in[13];
  const float* cmk    = (const float*)d_in[14];
  const float* cmr    = (const float*)d_in[15];
  const float* Wck    = (const float*)d_in[16];
  const float* Wcr    = (const float*)d_in[17];
  const float* Wcv    = (const float*)d_in[18];

  char* ws = (char*)d_ws;
  const size_t SZ = (size_t)M_ROWS * C_DIM * sizeof(_Float16);  // 32 MiB
  _Float16* B0 = (_Float16*)(ws + 0 * SZ);
  _Float16* B1 = (_Float16*)(ws + 1 * SZ);
  _Float16* B2 = (_Float16*)(ws + 2 * SZ);
  _Float16* B3 = (_Float16*)(ws + 3 * SZ);   // kk spans B3..B6 (128 MiB)
  _Float16* B4 = (_Float16*)(ws + 4 * SZ);
  _Float16* B5 = (_Float16*)(ws + 5 * SZ);
  _Float16* B6 = (_Float16*)(ws + 6 * SZ);
  _Float16* wWk  = (_Float16*)(ws + 7 * SZ);
  _Float16* wWv  = wWk  + (size_t)C_DIM * C_DIM;
  _Float16* wWr  = wWv  + (size_t)C_DIM * C_DIM;
  _Float16* wWo  = wWr  + (size_t)C_DIM * C_DIM;
  _Float16* wWcr = wWo  + (size_t)C_DIM * C_DIM;
  _Float16* wWck = wWcr + (size_t)C_DIM * C_DIM;
  _Float16* wWcv = wWck + (size_t)H_DIM * C_DIM;

  // fused weight cast: one launch for all 7 weights
  {
    CvtArgs a;
    const float* srcs[7] = {Wk, Wv, Wr, Wo, Wcr, Wck, Wcv};
    _Float16*    dsts[7] = {wWk, wWv, wWr, wWo, wWcr, wWck, wWcv};
    const size_t ns[7]   = {(size_t)C_DIM * C_DIM, (size_t)C_DIM * C_DIM,
                            (size_t)C_DIM * C_DIM, (size_t)C_DIM * C_DIM,
                            (size_t)C_DIM * C_DIM, (size_t)H_DIM * C_DIM,
                            (size_t)C_DIM * H_DIM};
    int st = 0;
    for (int j = 0; j < 7; ++j) {
      a.src[j] = srcs[j]; a.dst[j] = dsts[j];
      a.n4[j] = (int)(ns[j] / 4);
      a.start[j] = st;
      st += (a.n4[j] + 255) / 256;
    }
    a.start[7] = st;
    cvt_all_kernel<<<dim3(st), dim3(256), 0, stream>>>(a);
  }

  const dim3 blk(256);
  const dim3 gblk(512);
  const dim3 gN1(C_DIM / 256, M_ROWS / 256);      // (4, 64)
  const dim3 gKVR(C_DIM / 256, M_ROWS / 256, 3);  // batched k,v,r
  const dim3 gN4(H_DIM / 256, M_ROWS / 256);      // (16, 64)

  // --- TimeMix ---
  ln_kernel<<<dim3(M_ROWS / 4), blk, 0, stream>>>(x, ln1_g, ln1_b, B0);
  mix3_kernel<<<dim3(M_ROWS * 128 / 256), blk, 0, stream>>>(B0, amk, amv, amr, B1, B2, B3);
  // batched k,v,r projections: A = {B1,B2,B3}, B = {wWk,wWv,wWr}, C = {B4,B5,B6}
  gemm_nt_256<0><<<gKVR, gblk, 0, stream>>>(B1, wWk, B4, nullptr, nullptr,
      M_ROWS, C_DIM, C_DIM,
      (size_t)M_ROWS * C_DIM, (size_t)C_DIM * C_DIM,
      (size_t)M_ROWS * C_DIM * sizeof(_Float16));
  wkv_kernel<<<dim3(256), dim3(1024), 0, stream>>>(B4, B5, B6, tdec, tfirst, B1);
  gemm_nt_256<2><<<gN1, gblk, 0, stream>>>(B1, wWo, d_out, x, nullptr,
      M_ROWS, C_DIM, C_DIM, 0, 0, 0);

  // --- ChannelMix ---
  ln_kernel<<<dim3(M_ROWS / 4), blk, 0, stream>>>((const float*)d_out, ln2_g, ln2_b, B0);
  mix2_kernel<<<dim3(M_ROWS * 128 / 256), blk, 0, stream>>>(B0, cmk, cmr, B1, B2);
  gemm_nt_256<1><<<gN4, gblk, 0, stream>>>(B1, wWck, B3, nullptr, nullptr,
      M_ROWS, H_DIM, C_DIM, 0, 0, 0);
  gemm_nt_256<0><<<gN1, gblk, 0, stream>>>(B3, wWcv, B1, nullptr, nullptr,
      M_ROWS, C_DIM, H_DIM, 0, 0, 0);
  gemm_nt_256<3><<<gN1, gblk, 0, stream>>>(B2, wWcr, d_out, (const float*)d_out, B1,
      M_ROWS, C_DIM, C_DIM, 0, 0, 0);
}

// Round 11
// 636.488 us; speedup vs baseline: 1.0361x; 1.0284x over previous
//
#include <hip/hip_runtime.h>

#define T_SEQ 1024
#define C_DIM 1024
#define H_DIM 4096
#define M_ROWS 16384   // P*B*T = 2*8*1024
#define CHUNKS 16
#define CLEN 64        // T_SEQ / CHUNKS

typedef _Float16 f16x8 __attribute__((ext_vector_type(8)));
typedef _Float16 f16x4 __attribute__((ext_vector_type(4)));
typedef float    f32x4 __attribute__((ext_vector_type(4)));

#define AS1 __attribute__((address_space(1)))
#define AS3 __attribute__((address_space(3)))

__device__ __forceinline__ void gload_lds16(const void* g, void* l) {
  __builtin_amdgcn_global_load_lds((const AS1 void*)g, (AS3 void*)l, 16, 0, 0);
}

__device__ __forceinline__ float sigmoidf_(float x) {
  return 1.0f / (1.0f + __expf(-x));
}

// ---------------- fused weight f32 -> f16 (all 7 weights, one launch) --------
struct CvtArgs {
  const float* src[7];
  _Float16*    dst[7];
  int n4[7];       // elements/4 per source
  int start[8];    // block-range prefix
};

__global__ __launch_bounds__(256) void cvt_all_kernel(CvtArgs a) {
  const int bid = blockIdx.x;
  int s = 0;
#pragma unroll
  for (int j = 0; j < 7; ++j) s += (bid >= a.start[j + 1]) ? 1 : 0;
  const int i = (bid - a.start[s]) * 256 + threadIdx.x;
  if (i >= a.n4[s]) return;
  f32x4 v = reinterpret_cast<const f32x4*>(a.src[s])[i];
  f16x4 o;
  o[0] = (_Float16)v[0]; o[1] = (_Float16)v[1];
  o[2] = (_Float16)v[2]; o[3] = (_Float16)v[3];
  reinterpret_cast<f16x4*>(a.dst[s])[i] = o;
}

// ---------------- layernorm: f32 in -> f16 out (one wave per row) ----------------
__global__ __launch_bounds__(256) void ln_kernel(const float* __restrict__ x,
    const float* __restrict__ g, const float* __restrict__ b,
    _Float16* __restrict__ h) {
  const int row  = blockIdx.x * 4 + (threadIdx.x >> 6);
  const int lane = threadIdx.x & 63;
  const f32x4* xr = reinterpret_cast<const f32x4*>(x + (size_t)row * C_DIM);
  f32x4 v[4];
  float s = 0.f, sq = 0.f;
#pragma unroll
  for (int i = 0; i < 4; ++i) {
    v[i] = xr[i * 64 + lane];
#pragma unroll
    for (int j = 0; j < 4; ++j) { s += v[i][j]; sq += v[i][j] * v[i][j]; }
  }
#pragma unroll
  for (int off = 32; off > 0; off >>= 1) {
    s  += __shfl_xor(s, off, 64);
    sq += __shfl_xor(sq, off, 64);
  }
  const float mu   = s * (1.0f / C_DIM);
  const float var  = sq * (1.0f / C_DIM) - mu * mu;
  const float rstd = rsqrtf(var + 1e-5f);
  const f32x4* g4 = reinterpret_cast<const f32x4*>(g);
  const f32x4* b4 = reinterpret_cast<const f32x4*>(b);
  f16x4* h4 = reinterpret_cast<f16x4*>(h + (size_t)row * C_DIM);
#pragma unroll
  for (int i = 0; i < 4; ++i) {
    f32x4 gg = g4[i * 64 + lane];
    f32x4 bb = b4[i * 64 + lane];
    f16x4 o;
#pragma unroll
    for (int j = 0; j < 4; ++j)
      o[j] = (_Float16)((v[i][j] - mu) * rstd * gg[j] + bb[j]);
    h4[i * 64 + lane] = o;
  }
}

// ---------------- time-shift mix, 3 outputs ----------------
__global__ __launch_bounds__(256) void mix3_kernel(const _Float16* __restrict__ h,
    const float* __restrict__ mk, const float* __restrict__ mv, const float* __restrict__ mr,
    _Float16* __restrict__ xk, _Float16* __restrict__ xv, _Float16* __restrict__ xr) {
  const int i  = blockIdx.x * 256 + threadIdx.x;   // [0, M_ROWS*128)
  const int m  = i >> 7;
  const int c0 = (i & 127) << 3;
  const int p  = m >> 13;
  const int t  = m & (T_SEQ - 1);
  const f16x8* h8 = reinterpret_cast<const f16x8*>(h);
  f16x8 hc = h8[i];
  f16x8 hp;
#pragma unroll
  for (int j = 0; j < 8; ++j) hp[j] = (_Float16)0.f;
  if (t) hp = h8[i - 128];
  f16x8 ok, ov, orr;
#pragma unroll
  for (int j = 0; j < 8; ++j) {
    const float hcf = (float)hc[j], hpf = (float)hp[j];
    const float a = mk[p * C_DIM + c0 + j];
    const float c = mv[p * C_DIM + c0 + j];
    const float d = mr[p * C_DIM + c0 + j];
    ok[j]  = (_Float16)(hcf * a + hpf * (1.f - a));
    ov[j]  = (_Float16)(hcf * c + hpf * (1.f - c));
    orr[j] = (_Float16)(hcf * d + hpf * (1.f - d));
  }
  reinterpret_cast<f16x8*>(xk)[i] = ok;
  reinterpret_cast<f16x8*>(xv)[i] = ov;
  reinterpret_cast<f16x8*>(xr)[i] = orr;
}

// ---------------- time-shift mix, 2 outputs ----------------
__global__ __launch_bounds__(256) void mix2_kernel(const _Float16* __restrict__ h,
    const float* __restrict__ mk, const float* __restrict__ mr,
    _Float16* __restrict__ xk, _Float16* __restrict__ xr) {
  const int i  = blockIdx.x * 256 + threadIdx.x;
  const int m  = i >> 7;
  const int c0 = (i & 127) << 3;
  const int p  = m >> 13;
  const int t  = m & (T_SEQ - 1);
  const f16x8* h8 = reinterpret_cast<const f16x8*>(h);
  f16x8 hc = h8[i];
  f16x8 hp;
#pragma unroll
  for (int j = 0; j < 8; ++j) hp[j] = (_Float16)0.f;
  if (t) hp = h8[i - 128];
  f16x8 ok, orr;
#pragma unroll
  for (int j = 0; j < 8; ++j) {
    const float hcf = (float)hc[j], hpf = (float)hp[j];
    const float a = mk[p * C_DIM + c0 + j];
    const float d = mr[p * C_DIM + c0 + j];
    ok[j]  = (_Float16)(hcf * a + hpf * (1.f - a));
    orr[j] = (_Float16)(hcf * d + hpf * (1.f - d));
  }
  reinterpret_cast<f16x8*>(xk)[i] = ok;
  reinterpret_cast<f16x8*>(xr)[i] = orr;
}

// ---------------- WKV parallel chunked scan, fused with a = sigmoid(r)*y -------
__global__ __launch_bounds__(1024, 1) void wkv_kernel(const _Float16* __restrict__ k,
    const _Float16* __restrict__ v, const _Float16* __restrict__ r,
    const float* __restrict__ td, const float* __restrict__ tf,
    _Float16* __restrict__ a_out) {
  __shared__ float sA[CHUNKS][64];
  __shared__ float sB[CHUNKS][64];
  __shared__ float sP[CHUNKS][64];
  const int tid   = threadIdx.x;
  const int chunk = tid >> 6;
  const int ch    = tid & 63;
  const int n     = blockIdx.x >> 4;     // 16 sequences
  const int cg    = blockIdx.x & 15;     // 16 channel groups of 64
  const int c     = cg * 64 + ch;
  const float w = -__expf(td[c]);
  const float u = tf[c];
  const size_t cbase = (size_t)n * T_SEQ * C_DIM + (size_t)chunk * CLEN * C_DIM + c;

  // ---- phase 1: local chunk scan from empty state (state only) ----
  float aa = 0.f, bb = 0.f, pp = -1e38f;
  for (int s = 0; s < CLEN; ++s) {
    const size_t idx = cbase + (size_t)s * C_DIM;
    const float kk = (float)k[idx];
    const float vv = (float)v[idx];
    const float ww2 = w + pp;
    const float p2  = fmaxf(ww2, kk);
    const float e1b = __expf(ww2 - p2);
    const float e2b = __expf(kk - p2);
    aa = e1b * aa + e2b * vv;
    bb = e1b * bb + e2b;
    pp = p2;
  }
  sA[chunk][ch] = aa; sB[chunk][ch] = bb; sP[chunk][ch] = pp;
  __syncthreads();

  // ---- phase 2: exclusive prefix across chunks ----
  if (chunk == 0) {
    float pa = 0.f, pb = 0.f, ppr = -1e38f;
    const float wL = w * (float)CLEN;
    for (int j = 0; j < CHUNKS; ++j) {
      const float la = sA[j][ch], lb = sB[j][ch], lp = sP[j][ch];
      sA[j][ch] = pa; sB[j][ch] = pb; sP[j][ch] = ppr;
      const float dp = wL + ppr;
      const float np = fmaxf(dp, lp);
      const float e1 = __expf(dp - np);
      const float e2 = __expf(lp - np);
      pa  = e1 * pa + e2 * la;
      pb  = e1 * pb + e2 * lb;
      ppr = np;
    }
  }
  __syncthreads();

  // ---- phase 3: re-scan chunk from prefix state, emit sigmoid(r)*y ----
  aa = sA[chunk][ch]; bb = sB[chunk][ch]; pp = sP[chunk][ch];
  for (int s = 0; s < CLEN; ++s) {
    const size_t idx = cbase + (size_t)s * C_DIM;
    const float kk = (float)k[idx];
    const float vv = (float)v[idx];
    const float ww = u + kk;
    const float p  = fmaxf(pp, ww);
    const float e1 = __expf(pp - p);
    const float e2 = __expf(ww - p);
    const float yv = __fdividef(e1 * aa + e2 * vv, e1 * bb + e2);
    const float sr = sigmoidf_((float)r[idx]);
    a_out[idx] = (_Float16)(sr * yv);
    const float ww2 = w + pp;
    const float p2  = fmaxf(ww2, kk);
    const float e1b = __expf(ww2 - p2);
    const float e2b = __expf(kk - p2);
    aa = e1b * aa + e2b * vv;
    bb = e1b * bb + e2b;
    pp = p2;
  }
}

// ============ 256x256 GEMM, m201-faithful 4-phase schedule ============
// C[M,N] = A[M,K] * B[N,K]^T.  512 threads = 8 waves (2M x 4N), per-wave
// 128x64 output, BK=64, dbuf LDS [2][2][256*64] (row-split half-tiles:
// H0=Ah0 rows0-127, H1=Bh0, H2=Bh1, H3=Ah1; zero measured bank conflicts).
// Phase skeleton (reads PRE-barrier):
//   { ds-reads for this phase's quadrant; stage 1 half-tile;
//     [P0: lgkmcnt(8)] [P3: vmcnt gate]; barrier; lgkmcnt(0);
//     setprio(1); 16 MFMA; setprio(0); barrier }
// Quadrants: P0=(0,0) reads a0(8)+b0(4); P1=(0,1) reads b1(4);
// P2=(1,0) reads a1(8); P3=(1,1) reads none.
// vmcnt LEDGER (each STAGE = 2 loads — count LOADS, not stages; this was
// R10's bug: vmcnt(6) left H3(t+1) unforced -> race):
//   prologue: stage H0-H3(T0), H0,H1(T1) = 12 loads; vmcnt(4) forces the
//   8 of T0, leaves H0,H1(T1) in flight.
//   tile t: P0 stages H2(t+1), P1 H3(t+1), P2 H0(t+2), P3 H1(t+2) ->
//   12 outstanding at P3; vmcnt(4) forces the 8 oldest = ALL of tile t+1,
//   keeps H0,H1(t+2) = 4 loads in flight across the tile boundary.
//   Tails: t=NT-2 -> vmcnt(0) at P3 (conservative); t=NT-1 nothing staged.
// LDS overwrite hazards: each region's stage is >=2 closing-barriers after
// its last ds_read phase (Ah0:P0<-P2'', Bh0:P0<-P3'', Bh1:P1<-P0',
// Ah1:P2<-P1' — primes denote later tiles).
// EPI 0: f16; 1: f16(relu^2); 2: f32 acc+X; 3: f32 X + sigmoid(acc)*KV
#define GBAR() do { __builtin_amdgcn_sched_barrier(0); \
                    __builtin_amdgcn_s_barrier(); \
                    __builtin_amdgcn_sched_barrier(0); } while (0)
#define WVN(n) do { asm volatile("s_waitcnt vmcnt(" #n ")" ::: "memory"); \
                    __builtin_amdgcn_sched_barrier(0); } while (0)
#define WLN(n) do { asm volatile("s_waitcnt lgkmcnt(" #n ")" ::: "memory"); \
                    __builtin_amdgcn_sched_barrier(0); } while (0)
#define SCHED() __builtin_amdgcn_sched_barrier(0)
#define STAGE(op, SRC, row0, k0, bb) do { \
    _Pragma("unroll") \
    for (int c_ = 0; c_ < 2; ++c_) { \
      gload_lds16((SRC) + (size_t)((row0) + c_ * 64) * K + (k0), \
                  &lds[bb][op][((size_t)((row0) + c_ * 64) << 6) + dbase]); \
    } } while (0)
#define RD_AH(dst, mh) do { \
    _Pragma("unroll") for (int i_ = 0; i_ < 4; ++i_) \
    _Pragma("unroll") for (int k_ = 0; k_ < 2; ++k_) \
      dst[i_][k_] = *reinterpret_cast<const f16x8*>( \
        &lds[bi][0][((wr * 128 + (mh) * 64 + i_ * 16 + frow) << 6) + \
                    (((k_ << 5) + fk) ^ fxorh)]); \
  } while (0)
#define RD_BH(dst, nh) do { \
    _Pragma("unroll") for (int j_ = 0; j_ < 2; ++j_) \
    _Pragma("unroll") for (int k_ = 0; k_ < 2; ++k_) \
      dst[j_][k_] = *reinterpret_cast<const f16x8*>( \
        &lds[bi][1][((wcn * 64 + (nh) * 32 + j_ * 16 + frow) << 6) + \
                    (((k_ << 5) + fk) ^ fxorh)]); \
  } while (0)
#define MM16(asrc, bsrc, mh, nh) do { \
    __builtin_amdgcn_s_setprio(1); \
    _Pragma("unroll") for (int k_ = 0; k_ < 2; ++k_) \
    _Pragma("unroll") for (int i_ = 0; i_ < 4; ++i_) \
    _Pragma("unroll") for (int j_ = 0; j_ < 2; ++j_) \
      acc[(mh) * 4 + i_][(nh) * 2 + j_] = __builtin_amdgcn_mfma_f32_16x16x32_f16( \
        asrc[i_][k_], bsrc[j_][k_], acc[(mh) * 4 + i_][(nh) * 2 + j_], 0, 0, 0); \
    __builtin_amdgcn_s_setprio(0); \
  } while (0)

template<int EPI>
__global__ __launch_bounds__(512, 2) void gemm_nt_256(
    const _Float16* __restrict__ A, const _Float16* __restrict__ B,
    void* __restrict__ Cv, const float* __restrict__ X,
    const _Float16* __restrict__ KV, int M, int N, int K,
    size_t strideA, size_t strideB, size_t strideCbytes) {
  __shared__ _Float16 lds[2][2][256 * 64];
  const int tid  = threadIdx.x;
  const int wave = tid >> 6;
  const int lane = tid & 63;
  const int wr   = wave >> 2;     // 0..1
  const int wcn  = wave & 3;      // 0..3

  A  = A + (size_t)blockIdx.z * strideA;
  B  = B + (size_t)blockIdx.z * strideB;
  Cv = (void*)((char*)Cv + (size_t)blockIdx.z * strideCbytes);

  // XCD-bijective swizzle: XCD owns contiguous M chunk, n-fastest within.
  const unsigned nwx  = gridDim.x;        // N/256
  const unsigned pery = gridDim.y >> 3;   // m-tiles per XCD
  const unsigned id   = blockIdx.y * nwx + blockIdx.x;
  const unsigned xcd  = id & 7;
  const unsigned loc  = id >> 3;
  const size_t m0 = (size_t)(xcd * pery + loc / nwx) * 256;
  const size_t n0 = (size_t)(loc % nwx) * 256;

  // staging geometry: half-tile = 128 rows x 64 halfs; 2 gload_lds/thread;
  // LDS dest wave-uniform base + lane*16B (linear), T2 swizzle via source.
  const int srow  = tid >> 3;                       // 0..63
  const int scolh = ((tid & 7) ^ (srow & 7)) << 3;  // source-swizzled col (halfs)
  const size_t dbase = (size_t)(srow & ~7) << 6;    // wave-uniform
  const _Float16* sA = A + (m0 + srow) * (size_t)K + scolh;
  const _Float16* sB = B + (n0 + srow) * (size_t)K + scolh;

  // fragment geometry
  const int frow  = lane & 15;
  const int fk    = (lane >> 4) << 3;
  const int fxorh = (frow & 7) << 3;

  f32x4 acc[8][4];
#pragma unroll
  for (int i = 0; i < 8; ++i)
#pragma unroll
    for (int j = 0; j < 4; ++j) acc[i][j] = (f32x4){0.f, 0.f, 0.f, 0.f};

  const int NT = K >> 6;
  // prologue: H0-H3(T0) -> buf0, H0,H1(T1) -> buf1; vmcnt(4) forces T0.
  STAGE(0, sA, 0,   0, 0);
  STAGE(1, sB, 0,   0, 0);
  STAGE(1, sB, 128, 0, 0);
  STAGE(0, sA, 128, 0, 0);
  if (NT > 1) {
    STAGE(0, sA, 0, 64, 1);
    STAGE(1, sB, 0, 64, 1);
    WVN(4);
  } else {
    WVN(0);
  }
  GBAR();

  for (int t = 0; t < NT; ++t) {
    const int bi = t & 1;
    const int nb = bi ^ 1;
    const int k1 = (t + 1) << 6;
    const int k2 = (t + 2) << 6;
    const bool s1 = (t + 1) < NT;
    const bool s2 = (t + 2) < NT;
    f16x8 a0[4][2], a1[4][2], b0[2][2], b1[2][2];
    // ---- P0: Q(0,0); 12 reads pre-barrier ----
    RD_AH(a0, 0); RD_BH(b0, 0); SCHED();
    if (s1) STAGE(1, sB, 128, k1, nb);   // H2(t+1) = Bh1 -> nb
    WLN(8);
    GBAR();
    WLN(0);
    MM16(a0, b0, 0, 0);
    GBAR();
    // ---- P1: Q(0,1); 4 reads ----
    RD_BH(b1, 1); SCHED();
    if (s1) STAGE(0, sA, 128, k1, nb);   // H3(t+1) = Ah1 -> nb
    GBAR();
    WLN(0);
    MM16(a0, b1, 0, 1);
    GBAR();
    // ---- P2: Q(1,0); 8 reads ----
    RD_AH(a1, 1); SCHED();
    if (s2) STAGE(0, sA, 0, k2, bi);     // H0(t+2) = Ah0 -> bi
    GBAR();
    WLN(0);
    MM16(a1, b0, 1, 0);
    GBAR();
    // ---- P3: Q(1,1); 0 reads; end-of-tile vmcnt gate ----
    if (s2) {
      STAGE(1, sB, 0, k2, bi);           // H1(t+2) = Bh0 -> bi
      WVN(4);                            // 12 out - 4 kept = forces ALL of t+1
    } else {
      WVN(0);                            // tail: force remaining stages
    }
    GBAR();
    WLN(0);
    MM16(a1, b1, 1, 1);
    GBAR();
  }

  // epilogue: C/D layout (16x16): col = lane&15, row = (lane>>4)*4 + reg
  const int ecol  = lane & 15;
  const int erow4 = (lane >> 4) * 4;
#pragma unroll
  for (int mf = 0; mf < 8; ++mf)
#pragma unroll
    for (int nf = 0; nf < 4; ++nf) {
      const size_t rbase = m0 + (size_t)(wr * 128 + mf * 16 + erow4);
      const size_t cc    = n0 + (size_t)(wcn * 64 + nf * 16 + ecol);
#pragma unroll
      for (int r = 0; r < 4; ++r) {
        const float val = acc[mf][nf][r];
        const size_t off = (rbase + r) * (size_t)N + cc;
        if constexpr (EPI == 0) {
          ((_Float16*)Cv)[off] = (_Float16)val;
        } else if constexpr (EPI == 1) {
          const float tq = fmaxf(val, 0.f);
          ((_Float16*)Cv)[off] = (_Float16)(tq * tq);
        } else if constexpr (EPI == 2) {
          ((float*)Cv)[off] = val + X[off];
        } else {
          ((float*)Cv)[off] = X[off] + sigmoidf_(val) * (float)KV[off];
        }
      }
    }
}

extern "C" void kernel_launch(void* const* d_in, const int* in_sizes, int n_in,
                              void* d_out, int out_size, void* d_ws, size_t ws_size,
                              hipStream_t stream) {
  const float* x      = (const float*)d_in[0];
  const float* ln1_g  = (const float*)d_in[1];
  const float* ln1_b  = (const float*)d_in[2];
  const float* ln2_g  = (const float*)d_in[3];
  const float* ln2_b  = (const float*)d_in[4];
  const float* tdec   = (const float*)d_in[5];
  const float* tfirst = (const float*)d_in[6];
  const float* amk    = (const float*)d_in[7];
  const float* amv    = (const float*)d_in[8];
  const float* amr    = (const float*)d_in[9];
  const float* Wk     = (const float*)d_in[10];
  const float* Wv     = (const float*)d_in[11];
  const float* Wr     = (const float*)d_in[12];
  const float* Wo     = (const float*)d_in[13];
  const float* cmk    = (const float*)d_in[14];
  const float* cmr    = (const float*)d_in[15];
  const float* Wck    = (const float*)d_in[16];
  const float* Wcr    = (const float*)d_in[17];
  const float* Wcv    = (const float*)d_in[18];

  char* ws = (char*)d_ws;
  const size_t SZ = (size_t)M_ROWS * C_DIM * sizeof(_Float16);  // 32 MiB
  _Float16* B0 = (_Float16*)(ws + 0 * SZ);
  _Float16* B1 = (_Float16*)(ws + 1 * SZ);
  _Float16* B2 = (_Float16*)(ws + 2 * SZ);
  _Float16* B3 = (_Float16*)(ws + 3 * SZ);   // kk spans B3..B6 (128 MiB)
  _Float16* B4 = (_Float16*)(ws + 4 * SZ);
  _Float16* B5 = (_Float16*)(ws + 5 * SZ);
  _Float16* B6 = (_Float16*)(ws + 6 * SZ);
  _Float16* wWk  = (_Float16*)(ws + 7 * SZ);
  _Float16* wWv  = wWk  + (size_t)C_DIM * C_DIM;
  _Float16* wWr  = wWv  + (size_t)C_DIM * C_DIM;
  _Float16* wWo  = wWr  + (size_t)C_DIM * C_DIM;
  _Float16* wWcr = wWo  + (size_t)C_DIM * C_DIM;
  _Float16* wWck = wWcr + (size_t)C_DIM * C_DIM;
  _Float16* wWcv = wWck + (size_t)H_DIM * C_DIM;

  // fused weight cast: one launch for all 7 weights
  {
    CvtArgs a;
    const float* srcs[7] = {Wk, Wv, Wr, Wo, Wcr, Wck, Wcv};
    _Float16*    dsts[7] = {wWk, wWv, wWr, wWo, wWcr, wWck, wWcv};
    const size_t ns[7]   = {(size_t)C_DIM * C_DIM, (size_t)C_DIM * C_DIM,
                            (size_t)C_DIM * C_DIM, (size_t)C_DIM * C_DIM,
                            (size_t)C_DIM * C_DIM, (size_t)H_DIM * C_DIM,
                            (size_t)C_DIM * H_DIM};
    int st = 0;
    for (int j = 0; j < 7; ++j) {
      a.src[j] = srcs[j]; a.dst[j] = dsts[j];
      a.n4[j] = (int)(ns[j] / 4);
      a.start[j] = st;
      st += (a.n4[j] + 255) / 256;
    }
    a.start[7] = st;
    cvt_all_kernel<<<dim3(st), dim3(256), 0, stream>>>(a);
  }

  const dim3 blk(256);
  const dim3 gblk(512);
  const dim3 gN1(C_DIM / 256, M_ROWS / 256);      // (4, 64)
  const dim3 gKVR(C_DIM / 256, M_ROWS / 256, 3);  // batched k,v,r
  const dim3 gN4(H_DIM / 256, M_ROWS / 256);      // (16, 64)

  // --- TimeMix ---
  ln_kernel<<<dim3(M_ROWS / 4), blk, 0, stream>>>(x, ln1_g, ln1_b, B0);
  mix3_kernel<<<dim3(M_ROWS * 128 / 256), blk, 0, stream>>>(B0, amk, amv, amr, B1, B2, B3);
  // batched k,v,r projections: A = {B1,B2,B3}, B = {wWk,wWv,wWr}, C = {B4,B5,B6}
  gemm_nt_256<0><<<gKVR, gblk, 0, stream>>>(B1, wWk, B4, nullptr, nullptr,
      M_ROWS, C_DIM, C_DIM,
      (size_t)M_ROWS * C_DIM, (size_t)C_DIM * C_DIM,
      (size_t)M_ROWS * C_DIM * sizeof(_Float16));
  wkv_kernel<<<dim3(256), dim3(1024), 0, stream>>>(B4, B5, B6, tdec, tfirst, B1);
  gemm_nt_256<2><<<gN1, gblk, 0, stream>>>(B1, wWo, d_out, x, nullptr,
      M_ROWS, C_DIM, C_DIM, 0, 0, 0);

  // --- ChannelMix ---
  ln_kernel<<<dim3(M_ROWS / 4), blk, 0, stream>>>((const float*)d_out, ln2_g, ln2_b, B0);
  mix2_kernel<<<dim3(M_ROWS * 128 / 256), blk, 0, stream>>>(B0, cmk, cmr, B1, B2);
  gemm_nt_256<1><<<gN4, gblk, 0, stream>>>(B1, wWck, B3, nullptr, nullptr,
      M_ROWS, H_DIM, C_DIM, 0, 0, 0);
  gemm_nt_256<0><<<gN1, gblk, 0, stream>>>(B3, wWcv, B1, nullptr, nullptr,
      M_ROWS, C_DIM, H_DIM, 0, 0, 0);
  gemm_nt_256<3><<<gN1, gblk, 0, stream>>>(B2, wWcr, d_out, (const float*)d_out, B1,
      M_ROWS, C_DIM, C_DIM, 0, 0, 0);
}

// Round 12
// 622.314 us; speedup vs baseline: 1.0597x; 1.0228x over previous
//
#include <hip/hip_runtime.h>

#define T_SEQ 1024
#define C_DIM 1024
#define H_DIM 4096
#define M_ROWS 16384   // P*B*T = 2*8*1024
#define CHUNKS 16
#define CLEN 64        // T_SEQ / CHUNKS

typedef _Float16 f16x8 __attribute__((ext_vector_type(8)));
typedef _Float16 f16x4 __attribute__((ext_vector_type(4)));
typedef float    f32x4 __attribute__((ext_vector_type(4)));

#define AS1 __attribute__((address_space(1)))
#define AS3 __attribute__((address_space(3)))

__device__ __forceinline__ void gload_lds16(const void* g, void* l) {
  __builtin_amdgcn_global_load_lds((const AS1 void*)g, (AS3 void*)l, 16, 0, 0);
}

__device__ __forceinline__ float sigmoidf_(float x) {
  return 1.0f / (1.0f + __expf(-x));
}

// ---------------- fused weight f32 -> f16 (all 7 weights, one launch) --------
struct CvtArgs {
  const float* src[7];
  _Float16*    dst[7];
  int n4[7];       // elements/4 per source
  int start[8];    // block-range prefix
};

__global__ __launch_bounds__(256) void cvt_all_kernel(CvtArgs a) {
  const int bid = blockIdx.x;
  int s = 0;
#pragma unroll
  for (int j = 0; j < 7; ++j) s += (bid >= a.start[j + 1]) ? 1 : 0;
  const int i = (bid - a.start[s]) * 256 + threadIdx.x;
  if (i >= a.n4[s]) return;
  f32x4 v = reinterpret_cast<const f32x4*>(a.src[s])[i];
  f16x4 o;
  o[0] = (_Float16)v[0]; o[1] = (_Float16)v[1];
  o[2] = (_Float16)v[2]; o[3] = (_Float16)v[3];
  reinterpret_cast<f16x4*>(a.dst[s])[i] = o;
}

// ======== fused LayerNorm + time-shift mix (h never materialized) ========
// One wave per row m: computes LN(x[m]) AND LN(x[m-1]) (the time-shifted
// row; 0 at t==0), then the mix outputs directly. 8 waves/block -> reads
// rows [m0-1, m0+7] (9/8 amplification), writes only the mix outputs.
// NMIX=3: xk,xv,xr (TimeMix);  NMIX=2: xk,xr (ChannelMix).
template<int NMIX>
__global__ __launch_bounds__(512) void lnmix_kernel(const float* __restrict__ x,
    const float* __restrict__ g, const float* __restrict__ b,
    const float* __restrict__ mk, const float* __restrict__ mv,
    const float* __restrict__ mr,
    _Float16* __restrict__ xk, _Float16* __restrict__ xv,
    _Float16* __restrict__ xr) {
  const int wave = threadIdx.x >> 6;
  const int lane = threadIdx.x & 63;
  const int row  = blockIdx.x * 8 + wave;
  const int t    = row & (T_SEQ - 1);
  const int p    = row >> 13;
  const f32x4* x0 = reinterpret_cast<const f32x4*>(x + (size_t)row * C_DIM);
  const f32x4* x1 = reinterpret_cast<const f32x4*>(x + (size_t)(row - 1) * C_DIM);
  f32x4 vc[4], vp[4];
  float s0 = 0.f, q0 = 0.f, s1 = 0.f, q1 = 0.f;
#pragma unroll
  for (int i = 0; i < 4; ++i) {
    vc[i] = x0[i * 64 + lane];
#pragma unroll
    for (int j = 0; j < 4; ++j) { s0 += vc[i][j]; q0 += vc[i][j] * vc[i][j]; }
    if (t) {
      vp[i] = x1[i * 64 + lane];
#pragma unroll
      for (int j = 0; j < 4; ++j) { s1 += vp[i][j]; q1 += vp[i][j] * vp[i][j]; }
    }
  }
#pragma unroll
  for (int off = 32; off > 0; off >>= 1) {
    s0 += __shfl_xor(s0, off, 64);
    q0 += __shfl_xor(q0, off, 64);
    s1 += __shfl_xor(s1, off, 64);
    q1 += __shfl_xor(q1, off, 64);
  }
  const float mu0   = s0 * (1.0f / C_DIM);
  const float rstd0 = rsqrtf(q0 * (1.0f / C_DIM) - mu0 * mu0 + 1e-5f);
  const float mu1   = s1 * (1.0f / C_DIM);
  const float rstd1 = rsqrtf(q1 * (1.0f / C_DIM) - mu1 * mu1 + 1e-5f);
  const f32x4* g4  = reinterpret_cast<const f32x4*>(g);
  const f32x4* b4  = reinterpret_cast<const f32x4*>(b);
  const f32x4* mk4 = reinterpret_cast<const f32x4*>(mk + (size_t)p * C_DIM);
  const f32x4* mv4 = NMIX == 3 ? reinterpret_cast<const f32x4*>(mv + (size_t)p * C_DIM) : nullptr;
  const f32x4* mr4 = reinterpret_cast<const f32x4*>(mr + (size_t)p * C_DIM);
  f16x4* xk4 = reinterpret_cast<f16x4*>(xk) + (size_t)row * 256;
  f16x4* xv4 = NMIX == 3 ? reinterpret_cast<f16x4*>(xv) + (size_t)row * 256 : nullptr;
  f16x4* xr4 = reinterpret_cast<f16x4*>(xr) + (size_t)row * 256;
#pragma unroll
  for (int i = 0; i < 4; ++i) {
    const f32x4 gg = g4[i * 64 + lane];
    const f32x4 bb = b4[i * 64 + lane];
    const f32x4 ak = mk4[i * 64 + lane];
    const f32x4 ar = mr4[i * 64 + lane];
    f32x4 av;
    if (NMIX == 3) av = mv4[i * 64 + lane];
    f16x4 ok, ov, orr;
#pragma unroll
    for (int j = 0; j < 4; ++j) {
      const float hc = (vc[i][j] - mu0) * rstd0 * gg[j] + bb[j];
      const float hp = t ? ((vp[i][j] - mu1) * rstd1 * gg[j] + bb[j]) : 0.f;
      ok[j] = (_Float16)(hc * ak[j] + hp * (1.f - ak[j]));
      orr[j] = (_Float16)(hc * ar[j] + hp * (1.f - ar[j]));
      if (NMIX == 3) ov[j] = (_Float16)(hc * av[j] + hp * (1.f - av[j]));
    }
    xk4[i * 64 + lane] = ok;
    xr4[i * 64 + lane] = orr;
    if (NMIX == 3) xv4[i * 64 + lane] = ov;
  }
}

// ---------------- WKV parallel chunked scan, fused with a = sigmoid(r)*y -------
__global__ __launch_bounds__(1024, 1) void wkv_kernel(const _Float16* __restrict__ k,
    const _Float16* __restrict__ v, const _Float16* __restrict__ r,
    const float* __restrict__ td, const float* __restrict__ tf,
    _Float16* __restrict__ a_out) {
  __shared__ float sA[CHUNKS][64];
  __shared__ float sB[CHUNKS][64];
  __shared__ float sP[CHUNKS][64];
  const int tid   = threadIdx.x;
  const int chunk = tid >> 6;
  const int ch    = tid & 63;
  const int n     = blockIdx.x >> 4;     // 16 sequences
  const int cg    = blockIdx.x & 15;     // 16 channel groups of 64
  const int c     = cg * 64 + ch;
  const float w = -__expf(td[c]);
  const float u = tf[c];
  const size_t cbase = (size_t)n * T_SEQ * C_DIM + (size_t)chunk * CLEN * C_DIM + c;

  // ---- phase 1: local chunk scan from empty state (state only) ----
  float aa = 0.f, bb = 0.f, pp = -1e38f;
  for (int s = 0; s < CLEN; ++s) {
    const size_t idx = cbase + (size_t)s * C_DIM;
    const float kk = (float)k[idx];
    const float vv = (float)v[idx];
    const float ww2 = w + pp;
    const float p2  = fmaxf(ww2, kk);
    const float e1b = __expf(ww2 - p2);
    const float e2b = __expf(kk - p2);
    aa = e1b * aa + e2b * vv;
    bb = e1b * bb + e2b;
    pp = p2;
  }
  sA[chunk][ch] = aa; sB[chunk][ch] = bb; sP[chunk][ch] = pp;
  __syncthreads();

  // ---- phase 2: exclusive prefix across chunks ----
  if (chunk == 0) {
    float pa = 0.f, pb = 0.f, ppr = -1e38f;
    const float wL = w * (float)CLEN;
    for (int j = 0; j < CHUNKS; ++j) {
      const float la = sA[j][ch], lb = sB[j][ch], lp = sP[j][ch];
      sA[j][ch] = pa; sB[j][ch] = pb; sP[j][ch] = ppr;
      const float dp = wL + ppr;
      const float np = fmaxf(dp, lp);
      const float e1 = __expf(dp - np);
      const float e2 = __expf(lp - np);
      pa  = e1 * pa + e2 * la;
      pb  = e1 * pb + e2 * lb;
      ppr = np;
    }
  }
  __syncthreads();

  // ---- phase 3: re-scan chunk from prefix state, emit sigmoid(r)*y ----
  aa = sA[chunk][ch]; bb = sB[chunk][ch]; pp = sP[chunk][ch];
  for (int s = 0; s < CLEN; ++s) {
    const size_t idx = cbase + (size_t)s * C_DIM;
    const float kk = (float)k[idx];
    const float vv = (float)v[idx];
    const float ww = u + kk;
    const float p  = fmaxf(pp, ww);
    const float e1 = __expf(pp - p);
    const float e2 = __expf(ww - p);
    const float yv = __fdividef(e1 * aa + e2 * vv, e1 * bb + e2);
    const float sr = sigmoidf_((float)r[idx]);
    a_out[idx] = (_Float16)(sr * yv);
    const float ww2 = w + pp;
    const float p2  = fmaxf(ww2, kk);
    const float e1b = __expf(ww2 - p2);
    const float e2b = __expf(kk - p2);
    aa = e1b * aa + e2b * vv;
    bb = e1b * bb + e2b;
    pp = p2;
  }
}

// ============ 256x256 GEMM, 4-phase schedule (R11-passing; setprio REMOVED) ====
// C[M,N] = A[M,K] * B[N,K]^T.  512 threads = 8 waves (2M x 4N), per-wave
// 128x64 output, BK=64, dbuf LDS [2][2][256*64] (row-split half-tiles:
// H0=Ah0 rows0-127, H1=Bh0, H2=Bh1, H3=Ah1; zero measured bank conflicts).
// Phase skeleton (reads PRE-barrier):
//   { ds-reads for this phase's quadrant; stage 1 half-tile;
//     [P0: lgkmcnt(8)] [P3: vmcnt gate]; barrier; lgkmcnt(0);
//     16 MFMA; barrier }
// R12 change: setprio(1)/(0) around MFMA clusters REMOVED — with 2
// waves/SIMD, prio-1 MFMA may starve the other wave's prio-0 ds_read
// issue, serializing the LDS and matrix streams (the measured 38% = fully
// serialized component sum; setprio was negative on m190's GEMM regime).
// vmcnt LEDGER (counts LOADS, 2 per STAGE): prologue 12 loads, vmcnt(4)
// forces T0, keeps H0,H1(T1). Tile t: P0 stages H2(t+1), P1 H3(t+1),
// P2 H0(t+2), P3 H1(t+2) -> 12 outstanding; vmcnt(4) at P3 forces the 8
// oldest = ALL of tile t+1, keeps H0,H1(t+2) in flight. Tails conservative.
// LDS overwrite hazards: each region's stage >=2 closing-barriers after
// its last read phase.
// EPI 0: f16; 1: f16(relu^2); 2: f32 acc+X; 3: f32 X + sigmoid(acc)*KV
#define GBAR() do { __builtin_amdgcn_sched_barrier(0); \
                    __builtin_amdgcn_s_barrier(); \
                    __builtin_amdgcn_sched_barrier(0); } while (0)
#define WVN(n) do { asm volatile("s_waitcnt vmcnt(" #n ")" ::: "memory"); \
                    __builtin_amdgcn_sched_barrier(0); } while (0)
#define WLN(n) do { asm volatile("s_waitcnt lgkmcnt(" #n ")" ::: "memory"); \
                    __builtin_amdgcn_sched_barrier(0); } while (0)
#define SCHED() __builtin_amdgcn_sched_barrier(0)
#define STAGE(op, SRC, row0, k0, bb) do { \
    _Pragma("unroll") \
    for (int c_ = 0; c_ < 2; ++c_) { \
      gload_lds16((SRC) + (size_t)((row0) + c_ * 64) * K + (k0), \
                  &lds[bb][op][((size_t)((row0) + c_ * 64) << 6) + dbase]); \
    } } while (0)
#define RD_AH(dst, mh) do { \
    _Pragma("unroll") for (int i_ = 0; i_ < 4; ++i_) \
    _Pragma("unroll") for (int k_ = 0; k_ < 2; ++k_) \
      dst[i_][k_] = *reinterpret_cast<const f16x8*>( \
        &lds[bi][0][((wr * 128 + (mh) * 64 + i_ * 16 + frow) << 6) + \
                    (((k_ << 5) + fk) ^ fxorh)]); \
  } while (0)
#define RD_BH(dst, nh) do { \
    _Pragma("unroll") for (int j_ = 0; j_ < 2; ++j_) \
    _Pragma("unroll") for (int k_ = 0; k_ < 2; ++k_) \
      dst[j_][k_] = *reinterpret_cast<const f16x8*>( \
        &lds[bi][1][((wcn * 64 + (nh) * 32 + j_ * 16 + frow) << 6) + \
                    (((k_ << 5) + fk) ^ fxorh)]); \
  } while (0)
#define MM16(asrc, bsrc, mh, nh) do { \
    _Pragma("unroll") for (int k_ = 0; k_ < 2; ++k_) \
    _Pragma("unroll") for (int i_ = 0; i_ < 4; ++i_) \
    _Pragma("unroll") for (int j_ = 0; j_ < 2; ++j_) \
      acc[(mh) * 4 + i_][(nh) * 2 + j_] = __builtin_amdgcn_mfma_f32_16x16x32_f16( \
        asrc[i_][k_], bsrc[j_][k_], acc[(mh) * 4 + i_][(nh) * 2 + j_], 0, 0, 0); \
  } while (0)

template<int EPI>
__global__ __launch_bounds__(512, 2) void gemm_nt_256(
    const _Float16* __restrict__ A, const _Float16* __restrict__ B,
    void* __restrict__ Cv, const float* __restrict__ X,
    const _Float16* __restrict__ KV, int M, int N, int K,
    size_t strideA, size_t strideB, size_t strideCbytes) {
  __shared__ _Float16 lds[2][2][256 * 64];
  const int tid  = threadIdx.x;
  const int wave = tid >> 6;
  const int lane = tid & 63;
  const int wr   = wave >> 2;     // 0..1
  const int wcn  = wave & 3;      // 0..3

  A  = A + (size_t)blockIdx.z * strideA;
  B  = B + (size_t)blockIdx.z * strideB;
  Cv = (void*)((char*)Cv + (size_t)blockIdx.z * strideCbytes);

  // XCD-bijective swizzle: XCD owns contiguous M chunk, n-fastest within.
  const unsigned nwx  = gridDim.x;        // N/256
  const unsigned pery = gridDim.y >> 3;   // m-tiles per XCD
  const unsigned id   = blockIdx.y * nwx + blockIdx.x;
  const unsigned xcd  = id & 7;
  const unsigned loc  = id >> 3;
  const size_t m0 = (size_t)(xcd * pery + loc / nwx) * 256;
  const size_t n0 = (size_t)(loc % nwx) * 256;

  // staging geometry: half-tile = 128 rows x 64 halfs; 2 gload_lds/thread;
  // LDS dest wave-uniform base + lane*16B (linear), T2 swizzle via source.
  const int srow  = tid >> 3;                       // 0..63
  const int scolh = ((tid & 7) ^ (srow & 7)) << 3;  // source-swizzled col (halfs)
  const size_t dbase = (size_t)(srow & ~7) << 6;    // wave-uniform
  const _Float16* sA = A + (m0 + srow) * (size_t)K + scolh;
  const _Float16* sB = B + (n0 + srow) * (size_t)K + scolh;

  // fragment geometry
  const int frow  = lane & 15;
  const int fk    = (lane >> 4) << 3;
  const int fxorh = (frow & 7) << 3;

  f32x4 acc[8][4];
#pragma unroll
  for (int i = 0; i < 8; ++i)
#pragma unroll
    for (int j = 0; j < 4; ++j) acc[i][j] = (f32x4){0.f, 0.f, 0.f, 0.f};

  const int NT = K >> 6;
  // prologue: H0-H3(T0) -> buf0, H0,H1(T1) -> buf1; vmcnt(4) forces T0.
  STAGE(0, sA, 0,   0, 0);
  STAGE(1, sB, 0,   0, 0);
  STAGE(1, sB, 128, 0, 0);
  STAGE(0, sA, 128, 0, 0);
  if (NT > 1) {
    STAGE(0, sA, 0, 64, 1);
    STAGE(1, sB, 0, 64, 1);
    WVN(4);
  } else {
    WVN(0);
  }
  GBAR();

  for (int t = 0; t < NT; ++t) {
    const int bi = t & 1;
    const int nb = bi ^ 1;
    const int k1 = (t + 1) << 6;
    const int k2 = (t + 2) << 6;
    const bool s1 = (t + 1) < NT;
    const bool s2 = (t + 2) < NT;
    f16x8 a0[4][2], a1[4][2], b0[2][2], b1[2][2];
    // ---- P0: Q(0,0); 12 reads pre-barrier ----
    RD_AH(a0, 0); RD_BH(b0, 0); SCHED();
    if (s1) STAGE(1, sB, 128, k1, nb);   // H2(t+1) = Bh1 -> nb
    WLN(8);
    GBAR();
    WLN(0);
    MM16(a0, b0, 0, 0);
    GBAR();
    // ---- P1: Q(0,1); 4 reads ----
    RD_BH(b1, 1); SCHED();
    if (s1) STAGE(0, sA, 128, k1, nb);   // H3(t+1) = Ah1 -> nb
    GBAR();
    WLN(0);
    MM16(a0, b1, 0, 1);
    GBAR();
    // ---- P2: Q(1,0); 8 reads ----
    RD_AH(a1, 1); SCHED();
    if (s2) STAGE(0, sA, 0, k2, bi);     // H0(t+2) = Ah0 -> bi
    GBAR();
    WLN(0);
    MM16(a1, b0, 1, 0);
    GBAR();
    // ---- P3: Q(1,1); 0 reads; end-of-tile vmcnt gate ----
    if (s2) {
      STAGE(1, sB, 0, k2, bi);           // H1(t+2) = Bh0 -> bi
      WVN(4);                            // 12 out - 4 kept = forces ALL of t+1
    } else {
      WVN(0);                            // tail: force remaining stages
    }
    GBAR();
    WLN(0);
    MM16(a1, b1, 1, 1);
    GBAR();
  }

  // epilogue: C/D layout (16x16): col = lane&15, row = (lane>>4)*4 + reg
  const int ecol  = lane & 15;
  const int erow4 = (lane >> 4) * 4;
#pragma unroll
  for (int mf = 0; mf < 8; ++mf)
#pragma unroll
    for (int nf = 0; nf < 4; ++nf) {
      const size_t rbase = m0 + (size_t)(wr * 128 + mf * 16 + erow4);
      const size_t cc    = n0 + (size_t)(wcn * 64 + nf * 16 + ecol);
#pragma unroll
      for (int r = 0; r < 4; ++r) {
        const float val = acc[mf][nf][r];
        const size_t off = (rbase + r) * (size_t)N + cc;
        if constexpr (EPI == 0) {
          ((_Float16*)Cv)[off] = (_Float16)val;
        } else if constexpr (EPI == 1) {
          const float tq = fmaxf(val, 0.f);
          ((_Float16*)Cv)[off] = (_Float16)(tq * tq);
        } else if constexpr (EPI == 2) {
          ((float*)Cv)[off] = val + X[off];
        } else {
          ((float*)Cv)[off] = X[off] + sigmoidf_(val) * (float)KV[off];
        }
      }
    }
}

extern "C" void kernel_launch(void* const* d_in, const int* in_sizes, int n_in,
                              void* d_out, int out_size, void* d_ws, size_t ws_size,
                              hipStream_t stream) {
  const float* x      = (const float*)d_in[0];
  const float* ln1_g  = (const float*)d_in[1];
  const float* ln1_b  = (const float*)d_in[2];
  const float* ln2_g  = (const float*)d_in[3];
  const float* ln2_b  = (const float*)d_in[4];
  const float* tdec   = (const float*)d_in[5];
  const float* tfirst = (const float*)d_in[6];
  const float* amk    = (const float*)d_in[7];
  const float* amv    = (const float*)d_in[8];
  const float* amr    = (const float*)d_in[9];
  const float* Wk     = (const float*)d_in[10];
  const float* Wv     = (const float*)d_in[11];
  const float* Wr     = (const float*)d_in[12];
  const float* Wo     = (const float*)d_in[13];
  const float* cmk    = (const float*)d_in[14];
  const float* cmr    = (const float*)d_in[15];
  const float* Wck    = (const float*)d_in[16];
  const float* Wcr    = (const float*)d_in[17];
  const float* Wcv    = (const float*)d_in[18];

  char* ws = (char*)d_ws;
  const size_t SZ = (size_t)M_ROWS * C_DIM * sizeof(_Float16);  // 32 MiB
  _Float16* B0 = (_Float16*)(ws + 0 * SZ);
  _Float16* B1 = (_Float16*)(ws + 1 * SZ);
  _Float16* B2 = (_Float16*)(ws + 2 * SZ);
  _Float16* B3 = (_Float16*)(ws + 3 * SZ);   // kk spans B3..B6 (128 MiB)
  _Float16* B4 = (_Float16*)(ws + 4 * SZ);
  _Float16* B5 = (_Float16*)(ws + 5 * SZ);
  _Float16* B6 = (_Float16*)(ws + 6 * SZ);
  _Float16* wWk  = (_Float16*)(ws + 7 * SZ);
  _Float16* wWv  = wWk  + (size_t)C_DIM * C_DIM;
  _Float16* wWr  = wWv  + (size_t)C_DIM * C_DIM;
  _Float16* wWo  = wWr  + (size_t)C_DIM * C_DIM;
  _Float16* wWcr = wWo  + (size_t)C_DIM * C_DIM;
  _Float16* wWck = wWcr + (size_t)C_DIM * C_DIM;
  _Float16* wWcv = wWck + (size_t)H_DIM * C_DIM;

  // fused weight cast: one launch for all 7 weights
  {
    CvtArgs a;
    const float* srcs[7] = {Wk, Wv, Wr, Wo, Wcr, Wck, Wcv};
    _Float16*    dsts[7] = {wWk, wWv, wWr, wWo, wWcr, wWck, wWcv};
    const size_t ns[7]   = {(size_t)C_DIM * C_DIM, (size_t)C_DIM * C_DIM,
                            (size_t)C_DIM * C_DIM, (size_t)C_DIM * C_DIM,
                            (size_t)C_DIM * C_DIM, (size_t)H_DIM * C_DIM,
                            (size_t)C_DIM * H_DIM};
    int st = 0;
    for (int j = 0; j < 7; ++j) {
      a.src[j] = srcs[j]; a.dst[j] = dsts[j];
      a.n4[j] = (int)(ns[j] / 4);
      a.start[j] = st;
      st += (a.n4[j] + 255) / 256;
    }
    a.start[7] = st;
    cvt_all_kernel<<<dim3(st), dim3(256), 0, stream>>>(a);
  }

  const dim3 gblk(512);
  const dim3 gLN(M_ROWS / 8);                     // lnmix: 8 rows/block
  const dim3 gN1(C_DIM / 256, M_ROWS / 256);      // (4, 64)
  const dim3 gKVR(C_DIM / 256, M_ROWS / 256, 3);  // batched k,v,r
  const dim3 gN4(H_DIM / 256, M_ROWS / 256);      // (16, 64)

  // --- TimeMix ---
  lnmix_kernel<3><<<gLN, gblk, 0, stream>>>(x, ln1_g, ln1_b, amk, amv, amr,
                                            B1, B2, B3);
  // batched k,v,r projections: A = {B1,B2,B3}, B = {wWk,wWv,wWr}, C = {B4,B5,B6}
  gemm_nt_256<0><<<gKVR, gblk, 0, stream>>>(B1, wWk, B4, nullptr, nullptr,
      M_ROWS, C_DIM, C_DIM,
      (size_t)M_ROWS * C_DIM, (size_t)C_DIM * C_DIM,
      (size_t)M_ROWS * C_DIM * sizeof(_Float16));
  wkv_kernel<<<dim3(256), dim3(1024), 0, stream>>>(B4, B5, B6, tdec, tfirst, B1);
  gemm_nt_256<2><<<gN1, gblk, 0, stream>>>(B1, wWo, d_out, x, nullptr,
      M_ROWS, C_DIM, C_DIM, 0, 0, 0);

  // --- ChannelMix ---
  lnmix_kernel<2><<<gLN, gblk, 0, stream>>>((const float*)d_out, ln2_g, ln2_b,
                                            cmk, nullptr, cmr, B1, nullptr, B2);
  gemm_nt_256<1><<<gN4, gblk, 0, stream>>>(B1, wWck, B3, nullptr, nullptr,
      M_ROWS, H_DIM, C_DIM, 0, 0, 0);
  gemm_nt_256<0><<<gN1, gblk, 0, stream>>>(B3, wWcv, B1, nullptr, nullptr,
      M_ROWS, C_DIM, H_DIM, 0, 0, 0);
  gemm_nt_256<3><<<gN1, gblk, 0, stream>>>(B2, wWcr, d_out, (const float*)d_out, B1,
      M_ROWS, C_DIM, C_DIM, 0, 0, 0);
}